// Round 12
// baseline (145.373 us; speedup 1.0000x reference)
//
#include <hip/hip_runtime.h>

typedef _Float16 f16;
typedef _Float16 f16x2 __attribute__((ext_vector_type(2)));
typedef _Float16 f16x4 __attribute__((ext_vector_type(4)));
typedef _Float16 f16x8 __attribute__((ext_vector_type(8)));
typedef float    f32x4 __attribute__((ext_vector_type(4)));
typedef float    f32x16 __attribute__((ext_vector_type(16)));
typedef int      i32x4 __attribute__((ext_vector_type(4)));

#define NHEADS 16
#define DK 64
#define BATCH 2
#define SEQ 2048
#define DMODEL 1024
#define MTOT (BATCH*SEQ)          // 4096
#define NQKV (3*DMODEL)           // 3072
#define NBH  (BATCH*NHEADS)       // 32
#define LOG2E 1.44269504f
#define QSCALE (0.125f * LOG2E)   // fold 1/sqrt(dk) and log2(e) into Q
#define MASKVAL (-10000.0f * LOG2E)

__device__ inline f16x8 ld_f16x8_g(const f16* p) {
  return __builtin_bit_cast(f16x8, *reinterpret_cast<const i32x4*>(p));
}

__device__ inline f16x2 cvt_pk(float a, float b) {
  return __builtin_bit_cast(f16x2, __builtin_amdgcn_cvt_pkrtz(a, b));
}

__device__ inline void gl_lds16(const void* g, void* l) {
  __builtin_amdgcn_global_load_lds(
      (const __attribute__((address_space(1))) unsigned int*)g,
      (__attribute__((address_space(3))) unsigned int*)l, 16, 0, 0);
}

// ---------------- convert f32 -> f16, elementwise (n % 4 == 0) ----------------
__global__ void k_cvt(const float* __restrict__ in, f16* __restrict__ out, int n) {
  int i = (blockIdx.x * blockDim.x + threadIdx.x) * 4;
  if (i >= n) return;
  float4 v = *reinterpret_cast<const float4*>(in + i);
  f16x4 o = { (f16)v.x, (f16)v.y, (f16)v.z, (f16)v.w };
  *reinterpret_cast<f16x4*>(out + i) = o;
}

// ---------------- mask -> additive f32 bias in exp2 domain ----------------
__global__ void k_maskb(const int* __restrict__ mask, float* __restrict__ mb, int n) {
  int i = blockIdx.x * blockDim.x + threadIdx.x;
  if (i < n) mb[i] = mask[i] ? 0.f : MASKVAL;
}

// ------- transpose + convert: in f32 [K][N] -> out f16 [N][K] (K,N % 32 == 0) -------
__global__ void k_tcvt(const float* __restrict__ in, f16* __restrict__ out, int K, int N) {
  __shared__ float tile[32][33];
  int k0 = blockIdx.y * 32, n0 = blockIdx.x * 32;
  int tx = threadIdx.x, ty = threadIdx.y;   // block (32,8)
  #pragma unroll
  for (int i = 0; i < 4; ++i)
    tile[ty + 8*i][tx] = in[(size_t)(k0 + ty + 8*i) * N + n0 + tx];
  __syncthreads();
  #pragma unroll
  for (int i = 0; i < 4; ++i)
    out[(size_t)(n0 + ty + 8*i) * K + k0 + tx] = (f16)tile[tx][ty + 8*i];
}

// ---------------- GEMM: C[M,N] = A[M,K](f16) * Bt[N,K]^T(f16) + bias ----------------
// m97 structure + DOUBLE-BUFFERED LDS (v4-staging pattern): one barrier/iter,
// stage(t+1) issued before compute(t) so loads hide under 64 MFMAs.
// global_load_lds width-16, linear LDS dest, inverse-swizzled source + XOR reads.
template<int EPI>
__global__ __launch_bounds__(256, 2) void k_gemm(
    const f16* __restrict__ A, const f16* __restrict__ Bt,
    const float* __restrict__ bias,
    f16* __restrict__ qo, f16* __restrict__ ko, f16* __restrict__ vto,
    float* __restrict__ outf, int M, int N, int K)
{
  __shared__ f16 As[2][128][64];   // 32 KB
  __shared__ f16 Bs[2][128][64];   // 32 KB
  const int m0 = blockIdx.y * 128, n0 = blockIdx.x * 128;
  const int t = threadIdx.x;
  const int l = t & 63, w = t >> 6;
  const int wr = w >> 1, wc = w & 1;
  const int lc = l & 15, g = l >> 4;
  const int srow = l >> 3;                  // row within wave's 8-row stripe
  const int ssl  = ((l & 7) ^ srow) * 16;   // inverse-swizzled source byte slot
  const int swz  = (lc & 7) << 4;           // read-side XOR

  auto stage = [&](int buf, int kt) {
    #pragma unroll
    for (int it = 0; it < 4; ++it) {
      int row = it*32 + w*8 + srow;          // this lane's LDS row
      gl_lds16((const char*)(A  + (size_t)(m0 + row) * K + kt) + ssl,
               &As[buf][it*32 + w*8][0]);
      gl_lds16((const char*)(Bt + (size_t)(n0 + row) * K + kt) + ssl,
               &Bs[buf][it*32 + w*8][0]);
    }
  };

  f32x4 acc[4][4] = {};
  const int NT = K >> 6;
  stage(0, 0);

  for (int ti = 0; ti < NT; ++ti) {
    __syncthreads();                 // drains vmcnt -> buf[ti&1] ready
    if (ti + 1 < NT) stage((ti + 1) & 1, (ti + 1) * 64);
    const char* abase = (const char*)&As[ti & 1][0][0];
    const char* bbase = (const char*)&Bs[ti & 1][0][0];
    #pragma unroll
    for (int ks = 0; ks < 64; ks += 32) {
      f16x8 af[4], bf[4];
      #pragma unroll
      for (int i = 0; i < 4; ++i)
        af[i] = *(const f16x8*)(abase + (wr*64 + i*16 + lc)*128 + ((ks*2 + g*16) ^ swz));
      #pragma unroll
      for (int j = 0; j < 4; ++j)
        bf[j] = *(const f16x8*)(bbase + (wc*64 + j*16 + lc)*128 + ((ks*2 + g*16) ^ swz));
      #pragma unroll
      for (int i = 0; i < 4; ++i)
        #pragma unroll
        for (int j = 0; j < 4; ++j)
          acc[i][j] = __builtin_amdgcn_mfma_f32_16x16x32_f16(af[i], bf[j], acc[i][j], 0, 0, 0);
    }
  }

  const int lr4 = g * 4;   // C/D: row = g*4 + r, col = lc
  #pragma unroll
  for (int i = 0; i < 4; ++i) {
    #pragma unroll
    for (int j = 0; j < 4; ++j) {
      int col = n0 + wc*64 + j*16 + lc;
      float bv = bias[col];
      #pragma unroll
      for (int r = 0; r < 4; ++r) {
        int row = m0 + wr*64 + i*16 + lr4 + r;
        float v = acc[i][j][r] + bv;
        if (EPI == 0) {
          int which = col >> 10, h = (col >> 6) & 15, d = col & 63;
          int b = row >> 11, s = row & (SEQ - 1);
          size_t bh = (size_t)(b * NHEADS + h);
          if (which == 0)      qo[(bh * SEQ + s) * DK + d] = (f16)(v * QSCALE);
          else if (which == 1) ko[(bh * SEQ + s) * DK + d] = (f16)v;
          else {
            // V^T stored with sigma-permuted s within each 16-tile:
            // sigma(k) = swap bits 2 and 3 of k (involution, matches 32x32 PV B-frag)
            int sp = (s & ~12) | ((s & 4) << 1) | ((s & 8) >> 1);
            vto[(bh * DK + d) * SEQ + sp] = (f16)v;
          }
        } else {
          outf[(size_t)row * N + col] = v;
        }
      }
    }
  }
}

// ---------------- flash attention v8: 32x32 MFMA (best: 62.7 us) ----------------
// 512 blocks x 256 thr = 32 (b,h) * 16 q-blocks of 128; wave owns 32 q.
// LDS 32 KB: K/V 2-buf, PAIRED rows [32][256B] (row R = k|k+32) with 16-slot
// XOR swizzle. S^T via mfma(K,Q): lane holds ONE q with 32 k in regs -> scalar
// softmax. P in-register for PV (V columns bit2<->bit3 swapped in GEMM epilogue).
// Mask bias = QK C-init (zero VALU).
__global__ __launch_bounds__(256, 2) void k_attn8(
    const f16* __restrict__ Q, const f16* __restrict__ K,
    const f16* __restrict__ Vt, const float* __restrict__ mbias,
    f16* __restrict__ ctx)
{
  __shared__ f16 Kb[2][32][128];   // row R: k=R (128B) | k=R+32 (128B), swizzled
  __shared__ f16 Vb[2][32][128];   // row R: d=R | d=R+32

  // XCD-aware remap: bid%8 = XCD; each XCD owns 4 whole heads.
  const int bid = blockIdx.x;
  const int xcd = bid & 7, slot = bid >> 3;        // slot 0..63
  const int bh = xcd * 4 + (slot >> 4);            // 0..31
  const int qb = slot & 15;
  const int b  = bh >> 4, h = bh & (NHEADS - 1);
  const int t = threadIdx.x, l = t & 63, w = t >> 6;
  const int r31 = l & 31, hi = l >> 5;
  const int Rm = r31 & 15;
  const int q0 = qb * 128 + w * 32;

  const f16* Qp = Q + (size_t)bh * SEQ * DK;
  const f16* Kp = K + (size_t)bh * SEQ * DK;
  const f16* Vp = Vt + (size_t)bh * DK * SEQ;
  const float* mp = mbias + b * SEQ;

  // Q B-frags: col=q=r31, kdim d = ds*16 + hi*8 + j
  f16x8 qf[4];
  #pragma unroll
  for (int ds = 0; ds < 4; ++ds)
    qf[ds] = ld_f16x8_g(Qp + (size_t)(q0 + r31) * DK + ds*16 + hi*8);

  f32x16 o[2] = {};                 // O^T acc per d-tile (rows d, col q)
  float mrow = -3e38f;
  float lsum = 0.f;

  auto stage = [&](int buf, int kt) {
    #pragma unroll
    for (int c = 0; c < 2; ++c) {
      int Rbase = w*8 + c*4;
      int R = Rbase + (l >> 4);
      int u = (l & 15) ^ (R & 15);
      int off32 = (u >> 3) * 32;
      int byteoff = (u & 7) * 16;
      gl_lds16((const char*)Kp + (size_t)(kt + off32 + R) * (DK*2) + byteoff,
               &Kb[buf][Rbase][0]);
      gl_lds16((const char*)Vp + (size_t)(off32 + R) * (SEQ*2) + (size_t)kt*2 + byteoff,
               &Vb[buf][Rbase][0]);
    }
  };

  constexpr int NT = SEQ / 64;
  stage(0, 0);

  for (int it = 0; it < NT; ++it) {
    __syncthreads();                          // vmcnt(0)+lgkmcnt(0)+barrier
    if (it + 1 < NT) stage((it + 1) & 1, (it + 1) * 64);
    const int kt = it * 64;
    const char* kb = (const char*)&Kb[it & 1][0][0];
    const char* vb = (const char*)&Vb[it & 1][0][0];

    // --- bias -> QK C-init: reg r of tile T holds k=(r&3)+8*(r>>2)+4hi+32T ---
    f32x16 p[2];
    #pragma unroll
    for (int T = 0; T < 2; ++T) {
      const float* bp = mp + kt + T*32 + 4*hi;
      #pragma unroll
      for (int rq = 0; rq < 4; ++rq) {
        float4 bv = *reinterpret_cast<const float4*>(bp + rq*8);
        p[T][rq*4+0] = bv.x; p[T][rq*4+1] = bv.y;
        p[T][rq*4+2] = bv.z; p[T][rq*4+3] = bv.w;
      }
    }

    // --- S^T = K * Q^T + bias; A-frag row = k-row = r31 of tile T ---
    #pragma unroll
    for (int T = 0; T < 2; ++T)
      #pragma unroll
      for (int ds = 0; ds < 4; ++ds) {
        int slotc = T*8 + ds*2 + hi;
        f16x8 kf = *(const f16x8*)(kb + r31*256 + ((slotc ^ Rm) << 4));
        p[T] = __builtin_amdgcn_mfma_f32_32x32x16_f16(kf, qf[ds], p[T], 0, 0, 0);
      }

    // --- softmax max: pairwise tree then pair-lane combine ---
    float mx;
    {
      f32x4 t4;
      #pragma unroll
      for (int r = 0; r < 4; ++r)
        t4[r] = fmaxf(fmaxf(p[0][r], p[0][r+4]), fmaxf(p[0][r+8], p[0][r+12]));
      #pragma unroll
      for (int r = 0; r < 4; ++r)
        t4[r] = fmaxf(t4[r], fmaxf(fmaxf(p[1][r], p[1][r+4]), fmaxf(p[1][r+8], p[1][r+12])));
      mx = fmaxf(fmaxf(t4[0], t4[1]), fmaxf(t4[2], t4[3]));
    }
    mx = fmaxf(mx, __shfl_xor(mx, 32));

    if (!__all(mx <= mrow + 8.f)) {           // defer-max (T13), log2 domain
      float nm = fmaxf(mrow, mx);
      float sc = __builtin_amdgcn_exp2f(mrow - nm);
      mrow = nm;
      lsum *= sc;
      #pragma unroll
      for (int dt = 0; dt < 2; ++dt)
        #pragma unroll
        for (int r = 0; r < 16; ++r) o[dt][r] *= sc;
    }

    // --- P = exp2(S - m), pack pairs; partial sums for ILP ---
    f16x2 h2[2][8];
    float s0 = 0.f, s1 = 0.f;
    #pragma unroll
    for (int T = 0; T < 2; ++T)
      #pragma unroll
      for (int rp = 0; rp < 8; ++rp) {
        float e0 = __builtin_amdgcn_exp2f(p[T][2*rp]   - mrow);
        float e1 = __builtin_amdgcn_exp2f(p[T][2*rp+1] - mrow);
        s0 += e0; s1 += e1;
        h2[T][rp] = cvt_pk(e0, e1);
      }
    lsum += s0 + s1;

    // --- O^T += V^T * P : B-frag = own packed regs; kdim-16 index m = T*2+half ---
    #pragma unroll
    for (int T = 0; T < 2; ++T)
      #pragma unroll
      for (int half = 0; half < 2; ++half) {
        union { f16x2 a[4]; f16x8 v8; } pu;
        pu.a[0] = h2[T][half*4+0]; pu.a[1] = h2[T][half*4+1];
        pu.a[2] = h2[T][half*4+2]; pu.a[3] = h2[T][half*4+3];
        int m = T*2 + half;
        #pragma unroll
        for (int dt = 0; dt < 2; ++dt) {
          int slotc = dt*8 + m*2 + hi;
          f16x8 vf = *(const f16x8*)(vb + r31*256 + ((slotc ^ Rm) << 4));
          o[dt] = __builtin_amdgcn_mfma_f32_32x32x16_f16(vf, pu.v8, o[dt], 0, 0, 0);
        }
      }
  }

  // --- finalize: combine pair-lane sums, normalize, store ---
  lsum += __shfl_xor(lsum, 32);
  float inv = 1.f / lsum;
  f16* cp = ctx + (size_t)(b*SEQ + q0 + r31) * DMODEL + h*DK;
  #pragma unroll
  for (int dt = 0; dt < 2; ++dt)
    #pragma unroll
    for (int rq = 0; rq < 4; ++rq) {
      // regs 4rq..4rq+3 -> d = dt*32 + 8*rq + 4*hi + {0..3} (contiguous)
      union { f16x2 h2v[2]; f16x4 h4v; } u;
      u.h2v[0] = cvt_pk(o[dt][4*rq+0]*inv, o[dt][4*rq+1]*inv);
      u.h2v[1] = cvt_pk(o[dt][4*rq+2]*inv, o[dt][4*rq+3]*inv);
      *(f16x4*)(cp + dt*32 + 8*rq + 4*hi) = u.h4v;
    }
}

extern "C" void kernel_launch(void* const* d_in, const int* in_sizes, int n_in,
                              void* d_out, int out_size, void* d_ws, size_t ws_size,
                              hipStream_t stream) {
  const float* x    = (const float*)d_in[0];
  const int*   mask = (const int*)d_in[1];
  const float* Wqkv = (const float*)d_in[2];
  const float* bqkv = (const float*)d_in[3];
  const float* Wout = (const float*)d_in[4];
  const float* bout = (const float*)d_in[5];
  float* out = (float*)d_out;

  const size_t SZ_X    = (size_t)MTOT * DMODEL * 2;
  const size_t SZ_WQKV = (size_t)NQKV * DMODEL * 2;
  const size_t SZ_WOUT = (size_t)DMODEL * DMODEL * 2;
  const size_t SZ_QKV  = (size_t)BATCH * NHEADS * SEQ * DK * 2;
  const size_t SZ_MB   = (size_t)MTOT * 4;               // 4096 floats = 16 KB
  const size_t NEED = SZ_X + SZ_WQKV + SZ_WOUT + 3*SZ_QKV + SZ_X + SZ_MB;
  if (ws_size < NEED) return;

  char* p = (char*)d_ws;
  f16* xh    = (f16*)p; p += SZ_X;
  f16* Wqkvt = (f16*)p; p += SZ_WQKV;
  f16* Woutt = (f16*)p; p += SZ_WOUT;
  f16* Qh    = (f16*)p; p += SZ_QKV;
  f16* Kh    = (f16*)p; p += SZ_QKV;
  f16* Vth   = (f16*)p; p += SZ_QKV;
  f16* ctx   = (f16*)p; p += SZ_X;
  float* mb  = (float*)p; p += SZ_MB;

  k_cvt<<<(MTOT*DMODEL)/(256*4), 256, 0, stream>>>(x, xh, MTOT*DMODEL);
  k_maskb<<<(BATCH*SEQ + 255)/256, 256, 0, stream>>>(mask, mb, BATCH*SEQ);
  k_tcvt<<<dim3(NQKV/32, DMODEL/32), dim3(32,8), 0, stream>>>(Wqkv, Wqkvt, DMODEL, NQKV);
  k_tcvt<<<dim3(DMODEL/32, DMODEL/32), dim3(32,8), 0, stream>>>(Wout, Woutt, DMODEL, DMODEL);

  k_gemm<0><<<dim3(NQKV/128, MTOT/128), 256, 0, stream>>>(
      xh, Wqkvt, bqkv, Qh, Kh, Vth, nullptr, MTOT, NQKV, DMODEL);

  k_attn8<<<32 * 16, 256, 0, stream>>>(Qh, Kh, Vth, mb, ctx);

  k_gemm<1><<<dim3(DMODEL/128, MTOT/128), 256, 0, stream>>>(
      ctx, Woutt, bout, nullptr, nullptr, nullptr, out, MTOT, DMODEL, DMODEL);
}

// Round 13
// 124.261 us; speedup vs baseline: 1.1699x; 1.1699x over previous
//
#include <hip/hip_runtime.h>

typedef _Float16 f16;
typedef _Float16 f16x2 __attribute__((ext_vector_type(2)));
typedef _Float16 f16x4 __attribute__((ext_vector_type(4)));
typedef _Float16 f16x8 __attribute__((ext_vector_type(8)));
typedef float    f32x4 __attribute__((ext_vector_type(4)));
typedef float    f32x16 __attribute__((ext_vector_type(16)));
typedef int      i32x4 __attribute__((ext_vector_type(4)));

#define NHEADS 16
#define DK 64
#define BATCH 2
#define SEQ 2048
#define DMODEL 1024
#define MTOT (BATCH*SEQ)          // 4096
#define NQKV (3*DMODEL)           // 3072
#define NBH  (BATCH*NHEADS)       // 32
#define LOG2E 1.44269504f
#define QSCALE (0.125f * LOG2E)   // fold 1/sqrt(dk) and log2(e) into Q
#define MASKVAL (-10000.0f * LOG2E)

__device__ inline f16x8 ld_f16x8_g(const f16* p) {
  return __builtin_bit_cast(f16x8, *reinterpret_cast<const i32x4*>(p));
}

__device__ inline f16x2 cvt_pk(float a, float b) {
  return __builtin_bit_cast(f16x2, __builtin_amdgcn_cvt_pkrtz(a, b));
}

__device__ inline void gl_lds16(const void* g, void* l) {
  __builtin_amdgcn_global_load_lds(
      (const __attribute__((address_space(1))) unsigned int*)g,
      (__attribute__((address_space(3))) unsigned int*)l, 16, 0, 0);
}

// ---------------- convert f32 -> f16, elementwise (n % 4 == 0) ----------------
__global__ void k_cvt(const float* __restrict__ in, f16* __restrict__ out, int n) {
  int i = (blockIdx.x * blockDim.x + threadIdx.x) * 4;
  if (i >= n) return;
  float4 v = *reinterpret_cast<const float4*>(in + i);
  f16x4 o = { (f16)v.x, (f16)v.y, (f16)v.z, (f16)v.w };
  *reinterpret_cast<f16x4*>(out + i) = o;
}

// ---------------- mask -> additive f32 bias in exp2 domain ----------------
__global__ void k_maskb(const int* __restrict__ mask, float* __restrict__ mb, int n) {
  int i = blockIdx.x * blockDim.x + threadIdx.x;
  if (i < n) mb[i] = mask[i] ? 0.f : MASKVAL;
}

// ------- transpose + convert: in f32 [K][N] -> out f16 [N][K] (K,N % 32 == 0) -------
__global__ void k_tcvt(const float* __restrict__ in, f16* __restrict__ out, int K, int N) {
  __shared__ float tile[32][33];
  int k0 = blockIdx.y * 32, n0 = blockIdx.x * 32;
  int tx = threadIdx.x, ty = threadIdx.y;   // block (32,8)
  #pragma unroll
  for (int i = 0; i < 4; ++i)
    tile[ty + 8*i][tx] = in[(size_t)(k0 + ty + 8*i) * N + n0 + tx];
  __syncthreads();
  #pragma unroll
  for (int i = 0; i < 4; ++i)
    out[(size_t)(n0 + ty + 8*i) * K + k0 + tx] = (f16)tile[tx][ty + 8*i];
}

// ---------------- QKV GEMM: C[M,3072] = A[M,K] * Bt[3072,K]^T + bias --------------
// m97 structure, SINGLE-buffered (R9-proven): 128x128 tile, BK=64,
// global_load_lds width-16 into linear LDS, inverse-swizzled source + XOR reads.
// Epilogue: `which` hoisted (block-uniform); V^T stores vectorized f16x4.
__global__ __launch_bounds__(256, 2) void k_gemm_qkv(
    const f16* __restrict__ A, const f16* __restrict__ Bt,
    const float* __restrict__ bias,
    f16* __restrict__ qo, f16* __restrict__ ko, f16* __restrict__ vto, int K)
{
  __shared__ f16 As[128][64];   // linear, 16 KB
  __shared__ f16 Bs[128][64];   // linear, 16 KB
  const int m0 = blockIdx.y * 128, n0 = blockIdx.x * 128;
  const int t = threadIdx.x;
  const int l = t & 63, w = t >> 6;
  const int wr = w >> 1, wc = w & 1;
  const int lc = l & 15, g = l >> 4;
  const int srow = l >> 3;
  const int ssl  = ((l & 7) ^ srow) * 16;
  const int swz  = (lc & 7) << 4;

  f32x4 acc[4][4] = {};

  for (int kt = 0; kt < K; kt += 64) {
    __syncthreads();
    #pragma unroll
    for (int it = 0; it < 4; ++it) {
      int row = it*32 + w*8 + srow;
      gl_lds16((const char*)(A  + (size_t)(m0 + row) * K + kt) + ssl,
               &As[it*32 + w*8][0]);
      gl_lds16((const char*)(Bt + (size_t)(n0 + row) * K + kt) + ssl,
               &Bs[it*32 + w*8][0]);
    }
    __syncthreads();

    #pragma unroll
    for (int ks = 0; ks < 64; ks += 32) {
      f16x8 af[4], bf[4];
      #pragma unroll
      for (int i = 0; i < 4; ++i)
        af[i] = *(const f16x8*)((const char*)&As[wr*64 + i*16 + lc][0] + ((ks*2 + g*16) ^ swz));
      #pragma unroll
      for (int j = 0; j < 4; ++j)
        bf[j] = *(const f16x8*)((const char*)&Bs[wc*64 + j*16 + lc][0] + ((ks*2 + g*16) ^ swz));
      #pragma unroll
      for (int i = 0; i < 4; ++i)
        #pragma unroll
        for (int j = 0; j < 4; ++j)
          acc[i][j] = __builtin_amdgcn_mfma_f32_16x16x32_f16(af[i], bf[j], acc[i][j], 0, 0, 0);
    }
  }

  // --- epilogue: which = n0>>10 is block-uniform ---
  const int which = n0 >> 10;
  #pragma unroll
  for (int i = 0; i < 4; ++i) {
    const int row0 = m0 + wr*64 + i*16 + g*4;        // 4-aligned
    const int b = row0 >> 11, s0 = row0 & (SEQ - 1);
    #pragma unroll
    for (int j = 0; j < 4; ++j) {
      const int col = n0 + wc*64 + j*16 + lc;
      const float bv = bias[col];
      const int h = (col >> 6) & 15, d = col & 63;
      const size_t bh = (size_t)(b * NHEADS + h);
      if (which == 0) {
        #pragma unroll
        for (int r = 0; r < 4; ++r)
          qo[(bh * SEQ + s0 + r) * DK + d] = (f16)((acc[i][j][r] + bv) * QSCALE);
      } else if (which == 1) {
        #pragma unroll
        for (int r = 0; r < 4; ++r)
          ko[(bh * SEQ + s0 + r) * DK + d] = (f16)(acc[i][j][r] + bv);
      } else {
        // V^T with sigma(s)=swap bits 2,3; sp0+r consecutive -> f16x4 store
        int sp0 = (s0 & ~12) | ((s0 & 4) << 1) | ((s0 & 8) >> 1);
        union { f16x2 h2[2]; f16x4 h4; } u;
        u.h2[0] = cvt_pk(acc[i][j][0] + bv, acc[i][j][1] + bv);
        u.h2[1] = cvt_pk(acc[i][j][2] + bv, acc[i][j][3] + bv);
        *(f16x4*)(vto + (bh * DK + d) * SEQ + sp0) = u.h4;
      }
    }
  }
}

// ---------------- out-proj GEMM: C[M,1024] f32 = A[M,K] * Bt[1024,K]^T + bias -----
// 64x128 tile -> 512 blocks (2/CU) instead of 256 (1/CU). 24 KB LDS, 4 waves,
// wave owns 64x32 (acc[4][2]).
__global__ __launch_bounds__(256, 2) void k_gemm_out(
    const f16* __restrict__ A, const f16* __restrict__ Bt,
    const float* __restrict__ bias, float* __restrict__ outf, int N, int K)
{
  __shared__ f16 As[64][64];    // 8 KB
  __shared__ f16 Bs[128][64];   // 16 KB
  const int m0 = blockIdx.y * 64, n0 = blockIdx.x * 128;
  const int t = threadIdx.x;
  const int l = t & 63, w = t >> 6;
  const int lc = l & 15, g = l >> 4;
  const int srow = l >> 3;
  const int ssl  = ((l & 7) ^ srow) * 16;
  const int swz  = (lc & 7) << 4;

  f32x4 acc[4][2] = {};

  for (int kt = 0; kt < K; kt += 64) {
    __syncthreads();
    #pragma unroll
    for (int it = 0; it < 2; ++it) {
      int row = it*32 + w*8 + srow;
      gl_lds16((const char*)(A + (size_t)(m0 + row) * K + kt) + ssl,
               &As[it*32 + w*8][0]);
    }
    #pragma unroll
    for (int it = 0; it < 4; ++it) {
      int row = it*32 + w*8 + srow;
      gl_lds16((const char*)(Bt + (size_t)(n0 + row) * K + kt) + ssl,
               &Bs[it*32 + w*8][0]);
    }
    __syncthreads();

    #pragma unroll
    for (int ks = 0; ks < 64; ks += 32) {
      f16x8 af[4], bf[2];
      #pragma unroll
      for (int i = 0; i < 4; ++i)
        af[i] = *(const f16x8*)((const char*)&As[i*16 + lc][0] + ((ks*2 + g*16) ^ swz));
      #pragma unroll
      for (int j = 0; j < 2; ++j)
        bf[j] = *(const f16x8*)((const char*)&Bs[w*32 + j*16 + lc][0] + ((ks*2 + g*16) ^ swz));
      #pragma unroll
      for (int i = 0; i < 4; ++i)
        #pragma unroll
        for (int j = 0; j < 2; ++j)
          acc[i][j] = __builtin_amdgcn_mfma_f32_16x16x32_f16(af[i], bf[j], acc[i][j], 0, 0, 0);
    }
  }

  #pragma unroll
  for (int i = 0; i < 4; ++i) {
    #pragma unroll
    for (int j = 0; j < 2; ++j) {
      int col = n0 + w*32 + j*16 + lc;
      float bv = bias[col];
      #pragma unroll
      for (int r = 0; r < 4; ++r) {
        int row = m0 + i*16 + g*4 + r;
        outf[(size_t)row * N + col] = acc[i][j][r] + bv;
      }
    }
  }
}

// ---------------- flash attention v8 + T5 setprio (base: 62.7 us) ----------------
// 512 blocks x 256 thr = 32 (b,h) * 16 q-blocks of 128; wave owns 32 q.
// LDS 32 KB: K/V 2-buf, PAIRED rows [32][256B] with 16-slot XOR swizzle.
// S^T via mfma(K,Q): lane holds ONE q, 32 k in regs -> scalar softmax.
// P in-register for PV (V columns sigma-swapped in GEMM epilogue).
__global__ __launch_bounds__(256, 2) void k_attn8(
    const f16* __restrict__ Q, const f16* __restrict__ K,
    const f16* __restrict__ Vt, const float* __restrict__ mbias,
    f16* __restrict__ ctx)
{
  __shared__ f16 Kb[2][32][128];
  __shared__ f16 Vb[2][32][128];

  const int bid = blockIdx.x;
  const int xcd = bid & 7, slot = bid >> 3;        // slot 0..63
  const int bh = xcd * 4 + (slot >> 4);            // 0..31
  const int qb = slot & 15;
  const int b  = bh >> 4, h = bh & (NHEADS - 1);
  const int t = threadIdx.x, l = t & 63, w = t >> 6;
  const int r31 = l & 31, hi = l >> 5;
  const int Rm = r31 & 15;
  const int q0 = qb * 128 + w * 32;

  const f16* Qp = Q + (size_t)bh * SEQ * DK;
  const f16* Kp = K + (size_t)bh * SEQ * DK;
  const f16* Vp = Vt + (size_t)bh * DK * SEQ;
  const float* mp = mbias + b * SEQ;

  f16x8 qf[4];
  #pragma unroll
  for (int ds = 0; ds < 4; ++ds)
    qf[ds] = ld_f16x8_g(Qp + (size_t)(q0 + r31) * DK + ds*16 + hi*8);

  f32x16 o[2] = {};
  float mrow = -3e38f;
  float lsum = 0.f;

  auto stage = [&](int buf, int kt) {
    #pragma unroll
    for (int c = 0; c < 2; ++c) {
      int Rbase = w*8 + c*4;
      int R = Rbase + (l >> 4);
      int u = (l & 15) ^ (R & 15);
      int off32 = (u >> 3) * 32;
      int byteoff = (u & 7) * 16;
      gl_lds16((const char*)Kp + (size_t)(kt + off32 + R) * (DK*2) + byteoff,
               &Kb[buf][Rbase][0]);
      gl_lds16((const char*)Vp + (size_t)(off32 + R) * (SEQ*2) + (size_t)kt*2 + byteoff,
               &Vb[buf][Rbase][0]);
    }
  };

  constexpr int NT = SEQ / 64;
  stage(0, 0);

  for (int it = 0; it < NT; ++it) {
    __syncthreads();
    if (it + 1 < NT) stage((it + 1) & 1, (it + 1) * 64);
    const int kt = it * 64;
    const char* kb = (const char*)&Kb[it & 1][0][0];
    const char* vb = (const char*)&Vb[it & 1][0][0];

    f32x16 p[2];
    #pragma unroll
    for (int T = 0; T < 2; ++T) {
      const float* bp = mp + kt + T*32 + 4*hi;
      #pragma unroll
      for (int rq = 0; rq < 4; ++rq) {
        float4 bv = *reinterpret_cast<const float4*>(bp + rq*8);
        p[T][rq*4+0] = bv.x; p[T][rq*4+1] = bv.y;
        p[T][rq*4+2] = bv.z; p[T][rq*4+3] = bv.w;
      }
    }

    __builtin_amdgcn_s_setprio(1);
    #pragma unroll
    for (int T = 0; T < 2; ++T)
      #pragma unroll
      for (int ds = 0; ds < 4; ++ds) {
        int slotc = T*8 + ds*2 + hi;
        f16x8 kf = *(const f16x8*)(kb + r31*256 + ((slotc ^ Rm) << 4));
        p[T] = __builtin_amdgcn_mfma_f32_32x32x16_f16(kf, qf[ds], p[T], 0, 0, 0);
      }
    __builtin_amdgcn_s_setprio(0);

    float mx;
    {
      f32x4 t4;
      #pragma unroll
      for (int r = 0; r < 4; ++r)
        t4[r] = fmaxf(fmaxf(p[0][r], p[0][r+4]), fmaxf(p[0][r+8], p[0][r+12]));
      #pragma unroll
      for (int r = 0; r < 4; ++r)
        t4[r] = fmaxf(t4[r], fmaxf(fmaxf(p[1][r], p[1][r+4]), fmaxf(p[1][r+8], p[1][r+12])));
      mx = fmaxf(fmaxf(t4[0], t4[1]), fmaxf(t4[2], t4[3]));
    }
    mx = fmaxf(mx, __shfl_xor(mx, 32));

    if (!__all(mx <= mrow + 8.f)) {
      float nm = fmaxf(mrow, mx);
      float sc = __builtin_amdgcn_exp2f(mrow - nm);
      mrow = nm;
      lsum *= sc;
      #pragma unroll
      for (int dt = 0; dt < 2; ++dt)
        #pragma unroll
        for (int r = 0; r < 16; ++r) o[dt][r] *= sc;
    }

    f16x2 h2[2][8];
    float s0 = 0.f, s1 = 0.f;
    #pragma unroll
    for (int T = 0; T < 2; ++T)
      #pragma unroll
      for (int rp = 0; rp < 8; ++rp) {
        float e0 = __builtin_amdgcn_exp2f(p[T][2*rp]   - mrow);
        float e1 = __builtin_amdgcn_exp2f(p[T][2*rp+1] - mrow);
        s0 += e0; s1 += e1;
        h2[T][rp] = cvt_pk(e0, e1);
      }
    lsum += s0 + s1;

    __builtin_amdgcn_s_setprio(1);
    #pragma unroll
    for (int T = 0; T < 2; ++T)
      #pragma unroll
      for (int half = 0; half < 2; ++half) {
        union { f16x2 a[4]; f16x8 v8; } pu;
        pu.a[0] = h2[T][half*4+0]; pu.a[1] = h2[T][half*4+1];
        pu.a[2] = h2[T][half*4+2]; pu.a[3] = h2[T][half*4+3];
        int m = T*2 + half;
        #pragma unroll
        for (int dt = 0; dt < 2; ++dt) {
          int slotc = dt*8 + m*2 + hi;
          f16x8 vf = *(const f16x8*)(vb + r31*256 + ((slotc ^ Rm) << 4));
          o[dt] = __builtin_amdgcn_mfma_f32_32x32x16_f16(vf, pu.v8, o[dt], 0, 0, 0);
        }
      }
    __builtin_amdgcn_s_setprio(0);
  }

  lsum += __shfl_xor(lsum, 32);
  float inv = 1.f / lsum;
  f16* cp = ctx + (size_t)(b*SEQ + q0 + r31) * DMODEL + h*DK;
  #pragma unroll
  for (int dt = 0; dt < 2; ++dt)
    #pragma unroll
    for (int rq = 0; rq < 4; ++rq) {
      union { f16x2 h2v[2]; f16x4 h4v; } u;
      u.h2v[0] = cvt_pk(o[dt][4*rq+0]*inv, o[dt][4*rq+1]*inv);
      u.h2v[1] = cvt_pk(o[dt][4*rq+2]*inv, o[dt][4*rq+3]*inv);
      *(f16x4*)(cp + dt*32 + 8*rq + 4*hi) = u.h4v;
    }
}

extern "C" void kernel_launch(void* const* d_in, const int* in_sizes, int n_in,
                              void* d_out, int out_size, void* d_ws, size_t ws_size,
                              hipStream_t stream) {
  const float* x    = (const float*)d_in[0];
  const int*   mask = (const int*)d_in[1];
  const float* Wqkv = (const float*)d_in[2];
  const float* bqkv = (const float*)d_in[3];
  const float* Wout = (const float*)d_in[4];
  const float* bout = (const float*)d_in[5];
  float* out = (float*)d_out;

  const size_t SZ_X    = (size_t)MTOT * DMODEL * 2;
  const size_t SZ_WQKV = (size_t)NQKV * DMODEL * 2;
  const size_t SZ_WOUT = (size_t)DMODEL * DMODEL * 2;
  const size_t SZ_QKV  = (size_t)BATCH * NHEADS * SEQ * DK * 2;
  const size_t SZ_MB   = (size_t)MTOT * 4;               // 4096 floats = 16 KB
  const size_t NEED = SZ_X + SZ_WQKV + SZ_WOUT + 3*SZ_QKV + SZ_X + SZ_MB;
  if (ws_size < NEED) return;

  char* p = (char*)d_ws;
  f16* xh    = (f16*)p; p += SZ_X;
  f16* Wqkvt = (f16*)p; p += SZ_WQKV;
  f16* Woutt = (f16*)p; p += SZ_WOUT;
  f16* Qh    = (f16*)p; p += SZ_QKV;
  f16* Kh    = (f16*)p; p += SZ_QKV;
  f16* Vth   = (f16*)p; p += SZ_QKV;
  f16* ctx   = (f16*)p; p += SZ_X;
  float* mb  = (float*)p; p += SZ_MB;

  k_cvt<<<(MTOT*DMODEL)/(256*4), 256, 0, stream>>>(x, xh, MTOT*DMODEL);
  k_maskb<<<(BATCH*SEQ + 255)/256, 256, 0, stream>>>(mask, mb, BATCH*SEQ);
  k_tcvt<<<dim3(NQKV/32, DMODEL/32), dim3(32,8), 0, stream>>>(Wqkv, Wqkvt, DMODEL, NQKV);
  k_tcvt<<<dim3(DMODEL/32, DMODEL/32), dim3(32,8), 0, stream>>>(Wout, Woutt, DMODEL, DMODEL);

  k_gemm_qkv<<<dim3(NQKV/128, MTOT/128), 256, 0, stream>>>(
      xh, Wqkvt, bqkv, Qh, Kh, Vth, DMODEL);

  k_attn8<<<32 * 16, 256, 0, stream>>>(Qh, Kh, Vth, mb, ctx);

  k_gemm_out<<<dim3(DMODEL/128, MTOT/64), 256, 0, stream>>>(
      ctx, Woutt, bout, out, DMODEL, DMODEL);
}

// Round 14
// 110.829 us; speedup vs baseline: 1.3117x; 1.1212x over previous
//
#include <hip/hip_runtime.h>

typedef _Float16 f16;
typedef _Float16 f16x2 __attribute__((ext_vector_type(2)));
typedef _Float16 f16x4 __attribute__((ext_vector_type(4)));
typedef _Float16 f16x8 __attribute__((ext_vector_type(8)));
typedef float    f32x4 __attribute__((ext_vector_type(4)));
typedef float    f32x16 __attribute__((ext_vector_type(16)));
typedef int      i32x4 __attribute__((ext_vector_type(4)));

#define NHEADS 16
#define DK 64
#define BATCH 2
#define SEQ 2048
#define DMODEL 1024
#define MTOT (BATCH*SEQ)          // 4096
#define NQKV (3*DMODEL)           // 3072
#define NBH  (BATCH*NHEADS)       // 32
#define LOG2E 1.44269504f
#define QSCALE (0.125f * LOG2E)   // fold 1/sqrt(dk) and log2(e) into Q
#define MASKVAL (-10000.0f * LOG2E)

__device__ inline f16x8 ld_f16x8_g(const f16* p) {
  return __builtin_bit_cast(f16x8, *reinterpret_cast<const i32x4*>(p));
}

__device__ inline f16x2 cvt_pk(float a, float b) {
  return __builtin_bit_cast(f16x2, __builtin_amdgcn_cvt_pkrtz(a, b));
}

__device__ inline void gl_lds16(const void* g, void* l) {
  __builtin_amdgcn_global_load_lds(
      (const __attribute__((address_space(1))) unsigned int*)g,
      (__attribute__((address_space(3))) unsigned int*)l, 16, 0, 0);
}

// sigma: swap bits 2,3 (involution) -- the V^T column permutation for 32x32 PV
__device__ inline int sigma_k(int s) {
  return (s & ~12) | ((s & 4) << 1) | ((s & 8) >> 1);
}

// ---------------- convert f32 -> f16, elementwise (n % 4 == 0) ----------------
__global__ void k_cvt(const float* __restrict__ in, f16* __restrict__ out, int n) {
  int i = (blockIdx.x * blockDim.x + threadIdx.x) * 4;
  if (i >= n) return;
  float4 v = *reinterpret_cast<const float4*>(in + i);
  f16x4 o = { (f16)v.x, (f16)v.y, (f16)v.z, (f16)v.w };
  *reinterpret_cast<f16x4*>(out + i) = o;
}

// ------- per-batch exclusive prefix-sum of mask -> cpos (slot or -1), cnt -------
// 1 block per batch, 256 threads, 8 elems/thread, LDS Hillis-Steele. Deterministic.
__global__ __launch_bounds__(256) void k_scan(const int* __restrict__ mask,
                                              int* __restrict__ cpos,
                                              int* __restrict__ cnt) {
  __shared__ int part[256];
  const int b = blockIdx.x;
  const int t = threadIdx.x;
  const int* mp = mask + b * SEQ;
  int* cp = cpos + b * SEQ;
  const int base = t * 8;
  int m[8]; int s = 0;
  #pragma unroll
  for (int i = 0; i < 8; ++i) { m[i] = mp[base + i]; s += (m[i] != 0); }
  part[t] = s;
  __syncthreads();
  for (int d = 1; d < 256; d <<= 1) {
    int v = (t >= d) ? part[t - d] : 0;
    __syncthreads();
    part[t] += v;
    __syncthreads();
  }
  int pos = (t == 0) ? 0 : part[t - 1];
  #pragma unroll
  for (int i = 0; i < 8; ++i) {
    cp[base + i] = (m[i] != 0) ? pos : -1;
    pos += (m[i] != 0);
  }
  if (t == 255) cnt[b] = part[255];
}

// ------- zero pad rows [cnt, ceil64(cnt)) of compact K' (linear) and V' (sigma) ---
__global__ __launch_bounds__(256) void k_padzero(const int* __restrict__ cnt,
                                                 f16* __restrict__ ko,
                                                 f16* __restrict__ vto) {
  const int bh = blockIdx.x;            // 0..31
  const int b = bh >> 4;
  const int c = cnt[b];
  const int cpad = (c + 63) & ~63;
  const int npad = cpad - c;
  f16* kp = ko + (size_t)bh * SEQ * DK;
  f16* vp = vto + (size_t)bh * DK * SEQ;
  for (int idx = threadIdx.x; idx < npad * DK; idx += 256) {
    int slot = c + idx / DK, d = idx % DK;
    kp[(size_t)slot * DK + d] = (f16)0.f;
    vp[(size_t)d * SEQ + sigma_k(slot)] = (f16)0.f;
  }
}

// ------- transpose + convert: in f32 [K][N] -> out f16 [N][K] (K,N % 32 == 0) -------
__global__ void k_tcvt(const float* __restrict__ in, f16* __restrict__ out, int K, int N) {
  __shared__ float tile[32][33];
  int k0 = blockIdx.y * 32, n0 = blockIdx.x * 32;
  int tx = threadIdx.x, ty = threadIdx.y;   // block (32,8)
  #pragma unroll
  for (int i = 0; i < 4; ++i)
    tile[ty + 8*i][tx] = in[(size_t)(k0 + ty + 8*i) * N + n0 + tx];
  __syncthreads();
  #pragma unroll
  for (int i = 0; i < 4; ++i)
    out[(size_t)(n0 + ty + 8*i) * K + k0 + tx] = (f16)tile[tx][ty + 8*i];
}

// ---------------- QKV GEMM: C[M,3072] = A[M,K] * Bt[3072,K]^T + bias --------------
// m97 structure, single-buffered. Epilogue: Q full; K/V^T scattered to COMPACT
// slots via cpos (masked keys skipped); V^T at sigma(cpos).
__global__ __launch_bounds__(256, 2) void k_gemm_qkv(
    const f16* __restrict__ A, const f16* __restrict__ Bt,
    const float* __restrict__ bias, const int* __restrict__ cpos,
    f16* __restrict__ qo, f16* __restrict__ ko, f16* __restrict__ vto, int K)
{
  __shared__ f16 As[128][64];   // linear, 16 KB
  __shared__ f16 Bs[128][64];   // linear, 16 KB
  const int m0 = blockIdx.y * 128, n0 = blockIdx.x * 128;
  const int t = threadIdx.x;
  const int l = t & 63, w = t >> 6;
  const int wr = w >> 1, wc = w & 1;
  const int lc = l & 15, g = l >> 4;
  const int srow = l >> 3;
  const int ssl  = ((l & 7) ^ srow) * 16;
  const int swz  = (lc & 7) << 4;

  f32x4 acc[4][4] = {};

  for (int kt = 0; kt < K; kt += 64) {
    __syncthreads();
    #pragma unroll
    for (int it = 0; it < 4; ++it) {
      int row = it*32 + w*8 + srow;
      gl_lds16((const char*)(A  + (size_t)(m0 + row) * K + kt) + ssl,
               &As[it*32 + w*8][0]);
      gl_lds16((const char*)(Bt + (size_t)(n0 + row) * K + kt) + ssl,
               &Bs[it*32 + w*8][0]);
    }
    __syncthreads();

    #pragma unroll
    for (int ks = 0; ks < 64; ks += 32) {
      f16x8 af[4], bf[4];
      #pragma unroll
      for (int i = 0; i < 4; ++i)
        af[i] = *(const f16x8*)((const char*)&As[wr*64 + i*16 + lc][0] + ((ks*2 + g*16) ^ swz));
      #pragma unroll
      for (int j = 0; j < 4; ++j)
        bf[j] = *(const f16x8*)((const char*)&Bs[wc*64 + j*16 + lc][0] + ((ks*2 + g*16) ^ swz));
      #pragma unroll
      for (int i = 0; i < 4; ++i)
        #pragma unroll
        for (int j = 0; j < 4; ++j)
          acc[i][j] = __builtin_amdgcn_mfma_f32_16x16x32_f16(af[i], bf[j], acc[i][j], 0, 0, 0);
    }
  }

  // --- epilogue: which = n0>>10 is block-uniform ---
  const int which = n0 >> 10;
  #pragma unroll
  for (int i = 0; i < 4; ++i) {
    const int row0 = m0 + wr*64 + i*16 + g*4;        // 4-aligned
    const int b = row0 >> 11, s0 = row0 & (SEQ - 1);
    int4 cp4 = *reinterpret_cast<const int4*>(cpos + b*SEQ + s0);
    const int cpa[4] = {cp4.x, cp4.y, cp4.z, cp4.w};
    #pragma unroll
    for (int j = 0; j < 4; ++j) {
      const int col = n0 + wc*64 + j*16 + lc;
      const float bv = bias[col];
      const int h = (col >> 6) & 15, d = col & 63;
      const size_t bh = (size_t)(b * NHEADS + h);
      if (which == 0) {
        #pragma unroll
        for (int r = 0; r < 4; ++r)
          qo[(bh * SEQ + s0 + r) * DK + d] = (f16)((acc[i][j][r] + bv) * QSCALE);
      } else if (which == 1) {
        #pragma unroll
        for (int r = 0; r < 4; ++r)
          if (cpa[r] >= 0)
            ko[(bh * SEQ + cpa[r]) * DK + d] = (f16)(acc[i][j][r] + bv);
      } else {
        #pragma unroll
        for (int r = 0; r < 4; ++r)
          if (cpa[r] >= 0)
            vto[(bh * DK + d) * SEQ + sigma_k(cpa[r])] = (f16)(acc[i][j][r] + bv);
      }
    }
  }
}

// ---------------- out-proj GEMM: C[M,1024] f32 = A[M,K] * Bt[1024,K]^T + bias -----
__global__ __launch_bounds__(256, 2) void k_gemm_out(
    const f16* __restrict__ A, const f16* __restrict__ Bt,
    const float* __restrict__ bias, float* __restrict__ outf, int N, int K)
{
  __shared__ f16 As[64][64];    // 8 KB
  __shared__ f16 Bs[128][64];   // 16 KB
  const int m0 = blockIdx.y * 64, n0 = blockIdx.x * 128;
  const int t = threadIdx.x;
  const int l = t & 63, w = t >> 6;
  const int lc = l & 15, g = l >> 4;
  const int srow = l >> 3;
  const int ssl  = ((l & 7) ^ srow) * 16;
  const int swz  = (lc & 7) << 4;

  f32x4 acc[4][2] = {};

  for (int kt = 0; kt < K; kt += 64) {
    __syncthreads();
    #pragma unroll
    for (int it = 0; it < 2; ++it) {
      int row = it*32 + w*8 + srow;
      gl_lds16((const char*)(A + (size_t)(m0 + row) * K + kt) + ssl,
               &As[it*32 + w*8][0]);
    }
    #pragma unroll
    for (int it = 0; it < 4; ++it) {
      int row = it*32 + w*8 + srow;
      gl_lds16((const char*)(Bt + (size_t)(n0 + row) * K + kt) + ssl,
               &Bs[it*32 + w*8][0]);
    }
    __syncthreads();

    #pragma unroll
    for (int ks = 0; ks < 64; ks += 32) {
      f16x8 af[4], bf[2];
      #pragma unroll
      for (int i = 0; i < 4; ++i)
        af[i] = *(const f16x8*)((const char*)&As[i*16 + lc][0] + ((ks*2 + g*16) ^ swz));
      #pragma unroll
      for (int j = 0; j < 2; ++j)
        bf[j] = *(const f16x8*)((const char*)&Bs[w*32 + j*16 + lc][0] + ((ks*2 + g*16) ^ swz));
      #pragma unroll
      for (int i = 0; i < 4; ++i)
        #pragma unroll
        for (int j = 0; j < 2; ++j)
          acc[i][j] = __builtin_amdgcn_mfma_f32_16x16x32_f16(af[i], bf[j], acc[i][j], 0, 0, 0);
    }
  }

  #pragma unroll
  for (int i = 0; i < 4; ++i) {
    #pragma unroll
    for (int j = 0; j < 2; ++j) {
      int col = n0 + w*32 + j*16 + lc;
      float bv = bias[col];
      #pragma unroll
      for (int r = 0; r < 4; ++r) {
        int row = m0 + i*16 + g*4 + r;
        outf[(size_t)row * N + col] = acc[i][j][r] + bv;
      }
    }
  }
}

// ---------------- flash attention v10: 32x32 MFMA over COMPACTED keys ------------
// 512 blocks x 256 thr; wave owns 32 q. K'/V' hold only unmasked keys (cnt[b]),
// pad rows zeroed. No mask bias in main loop (C-init 0); last tile biases pads.
__global__ __launch_bounds__(256, 2) void k_attn10(
    const f16* __restrict__ Q, const f16* __restrict__ K,
    const f16* __restrict__ Vt, const int* __restrict__ cnt,
    f16* __restrict__ ctx)
{
  __shared__ f16 Kb[2][32][128];
  __shared__ f16 Vb[2][32][128];

  const int bid = blockIdx.x;
  const int xcd = bid & 7, slot = bid >> 3;        // slot 0..63
  const int bh = xcd * 4 + (slot >> 4);            // 0..31
  const int qb = slot & 15;
  const int b  = bh >> 4, h = bh & (NHEADS - 1);
  const int t = threadIdx.x, l = t & 63, w = t >> 6;
  const int r31 = l & 31, hi = l >> 5;
  const int Rm = r31 & 15;
  const int q0 = qb * 128 + w * 32;

  const int c = cnt[b];
  const int NTc = (c + 63) >> 6;

  const f16* Qp = Q + (size_t)bh * SEQ * DK;
  const f16* Kp = K + (size_t)bh * SEQ * DK;
  const f16* Vp = Vt + (size_t)bh * DK * SEQ;

  f16x8 qf[4];
  #pragma unroll
  for (int ds = 0; ds < 4; ++ds)
    qf[ds] = ld_f16x8_g(Qp + (size_t)(q0 + r31) * DK + ds*16 + hi*8);

  f32x16 o[2] = {};
  float mrow = -3e38f;
  float lsum = 0.f;

  auto stage = [&](int buf, int kt) {
    #pragma unroll
    for (int cc = 0; cc < 2; ++cc) {
      int Rbase = w*8 + cc*4;
      int R = Rbase + (l >> 4);
      int u = (l & 15) ^ (R & 15);
      int off32 = (u >> 3) * 32;
      int byteoff = (u & 7) * 16;
      gl_lds16((const char*)Kp + (size_t)(kt + off32 + R) * (DK*2) + byteoff,
               &Kb[buf][Rbase][0]);
      gl_lds16((const char*)Vp + (size_t)(off32 + R) * (SEQ*2) + (size_t)kt*2 + byteoff,
               &Vb[buf][Rbase][0]);
    }
  };

  stage(0, 0);

  for (int it = 0; it < NTc; ++it) {
    __syncthreads();
    if (it + 1 < NTc) stage((it + 1) & 1, (it + 1) * 64);
    const int kt = it * 64;
    const char* kb = (const char*)&Kb[it & 1][0][0];
    const char* vb = (const char*)&Vb[it & 1][0][0];

    // --- C-init: 0 for full tiles; pad bias on the last tile ---
    f32x16 p[2];
    if (kt + 64 <= c) {
      #pragma unroll
      for (int T = 0; T < 2; ++T)
        #pragma unroll
        for (int r = 0; r < 16; ++r) p[T][r] = 0.f;
    } else {
      #pragma unroll
      for (int T = 0; T < 2; ++T)
        #pragma unroll
        for (int r = 0; r < 16; ++r) {
          int k = kt + T*32 + 4*hi + (r & 3) + 8*(r >> 2);
          p[T][r] = (k < c) ? 0.f : MASKVAL;
        }
    }

    __builtin_amdgcn_s_setprio(1);
    #pragma unroll
    for (int T = 0; T < 2; ++T)
      #pragma unroll
      for (int ds = 0; ds < 4; ++ds) {
        int slotc = T*8 + ds*2 + hi;
        f16x8 kf = *(const f16x8*)(kb + r31*256 + ((slotc ^ Rm) << 4));
        p[T] = __builtin_amdgcn_mfma_f32_32x32x16_f16(kf, qf[ds], p[T], 0, 0, 0);
      }
    __builtin_amdgcn_s_setprio(0);

    float mx;
    {
      f32x4 t4;
      #pragma unroll
      for (int r = 0; r < 4; ++r)
        t4[r] = fmaxf(fmaxf(p[0][r], p[0][r+4]), fmaxf(p[0][r+8], p[0][r+12]));
      #pragma unroll
      for (int r = 0; r < 4; ++r)
        t4[r] = fmaxf(t4[r], fmaxf(fmaxf(p[1][r], p[1][r+4]), fmaxf(p[1][r+8], p[1][r+12])));
      mx = fmaxf(fmaxf(t4[0], t4[1]), fmaxf(t4[2], t4[3]));
    }
    mx = fmaxf(mx, __shfl_xor(mx, 32));

    if (!__all(mx <= mrow + 8.f)) {
      float nm = fmaxf(mrow, mx);
      float sc = __builtin_amdgcn_exp2f(mrow - nm);
      mrow = nm;
      lsum *= sc;
      #pragma unroll
      for (int dt = 0; dt < 2; ++dt)
        #pragma unroll
        for (int r = 0; r < 16; ++r) o[dt][r] *= sc;
    }

    f16x2 h2[2][8];
    float s0 = 0.f, s1 = 0.f;
    #pragma unroll
    for (int T = 0; T < 2; ++T)
      #pragma unroll
      for (int rp = 0; rp < 8; ++rp) {
        float e0 = __builtin_amdgcn_exp2f(p[T][2*rp]   - mrow);
        float e1 = __builtin_amdgcn_exp2f(p[T][2*rp+1] - mrow);
        s0 += e0; s1 += e1;
        h2[T][rp] = cvt_pk(e0, e1);
      }
    lsum += s0 + s1;

    __builtin_amdgcn_s_setprio(1);
    #pragma unroll
    for (int T = 0; T < 2; ++T)
      #pragma unroll
      for (int half = 0; half < 2; ++half) {
        union { f16x2 a[4]; f16x8 v8; } pu;
        pu.a[0] = h2[T][half*4+0]; pu.a[1] = h2[T][half*4+1];
        pu.a[2] = h2[T][half*4+2]; pu.a[3] = h2[T][half*4+3];
        int m = T*2 + half;
        #pragma unroll
        for (int dt = 0; dt < 2; ++dt) {
          int slotc = dt*8 + m*2 + hi;
          f16x8 vf = *(const f16x8*)(vb + r31*256 + ((slotc ^ Rm) << 4));
          o[dt] = __builtin_amdgcn_mfma_f32_32x32x16_f16(vf, pu.v8, o[dt], 0, 0, 0);
        }
      }
    __builtin_amdgcn_s_setprio(0);
  }

  lsum += __shfl_xor(lsum, 32);
  float inv = 1.f / lsum;
  f16* cp = ctx + (size_t)(b*SEQ + q0 + r31) * DMODEL + h*DK;
  #pragma unroll
  for (int dt = 0; dt < 2; ++dt)
    #pragma unroll
    for (int rq = 0; rq < 4; ++rq) {
      union { f16x2 h2v[2]; f16x4 h4v; } u;
      u.h2v[0] = cvt_pk(o[dt][4*rq+0]*inv, o[dt][4*rq+1]*inv);
      u.h2v[1] = cvt_pk(o[dt][4*rq+2]*inv, o[dt][4*rq+3]*inv);
      *(f16x4*)(cp + dt*32 + 8*rq + 4*hi) = u.h4v;
    }
}

extern "C" void kernel_launch(void* const* d_in, const int* in_sizes, int n_in,
                              void* d_out, int out_size, void* d_ws, size_t ws_size,
                              hipStream_t stream) {
  const float* x    = (const float*)d_in[0];
  const int*   mask = (const int*)d_in[1];
  const float* Wqkv = (const float*)d_in[2];
  const float* bqkv = (const float*)d_in[3];
  const float* Wout = (const float*)d_in[4];
  const float* bout = (const float*)d_in[5];
  float* out = (float*)d_out;

  const size_t SZ_X    = (size_t)MTOT * DMODEL * 2;
  const size_t SZ_WQKV = (size_t)NQKV * DMODEL * 2;
  const size_t SZ_WOUT = (size_t)DMODEL * DMODEL * 2;
  const size_t SZ_QKV  = (size_t)BATCH * NHEADS * SEQ * DK * 2;
  const size_t SZ_CP   = (size_t)MTOT * 4;    // cpos: 4096 ints = 16 KB
  const size_t SZ_CNT  = 256;                 // cnt: 2 ints, padded
  const size_t NEED = SZ_X + SZ_WQKV + SZ_WOUT + 3*SZ_QKV + SZ_X + SZ_CP + SZ_CNT;
  if (ws_size < NEED) return;

  char* p = (char*)d_ws;
  f16* xh    = (f16*)p; p += SZ_X;
  f16* Wqkvt = (f16*)p; p += SZ_WQKV;
  f16* Woutt = (f16*)p; p += SZ_WOUT;
  f16* Qh    = (f16*)p; p += SZ_QKV;
  f16* Kh    = (f16*)p; p += SZ_QKV;
  f16* Vth   = (f16*)p; p += SZ_QKV;
  f16* ctx   = (f16*)p; p += SZ_X;
  int* cpos  = (int*)p; p += SZ_CP;
  int* cnt   = (int*)p; p += SZ_CNT;

  k_cvt<<<(MTOT*DMODEL)/(256*4), 256, 0, stream>>>(x, xh, MTOT*DMODEL);
  k_scan<<<BATCH, 256, 0, stream>>>(mask, cpos, cnt);
  k_padzero<<<NBH, 256, 0, stream>>>(cnt, Kh, Vth);
  k_tcvt<<<dim3(NQKV/32, DMODEL/32), dim3(32,8), 0, stream>>>(Wqkv, Wqkvt, DMODEL, NQKV);
  k_tcvt<<<dim3(DMODEL/32, DMODEL/32), dim3(32,8), 0, stream>>>(Wout, Woutt, DMODEL, DMODEL);

  k_gemm_qkv<<<dim3(NQKV/128, MTOT/128), 256, 0, stream>>>(
      xh, Wqkvt, bqkv, cpos, Qh, Kh, Vth, DMODEL);

  k_attn10<<<32 * 16, 256, 0, stream>>>(Qh, Kh, Vth, cnt, ctx);

  k_gemm_out<<<dim3(DMODEL/128, MTOT/64), 256, 0, stream>>>(
      ctx, Woutt, bout, out, DMODEL, DMODEL);
}

// Round 15
// 104.013 us; speedup vs baseline: 1.3976x; 1.0655x over previous
//
#include <hip/hip_runtime.h>

typedef _Float16 f16;
typedef _Float16 f16x2 __attribute__((ext_vector_type(2)));
typedef _Float16 f16x4 __attribute__((ext_vector_type(4)));
typedef _Float16 f16x8 __attribute__((ext_vector_type(8)));
typedef float    f32x4 __attribute__((ext_vector_type(4)));
typedef float    f32x16 __attribute__((ext_vector_type(16)));
typedef int      i32x4 __attribute__((ext_vector_type(4)));

#define NHEADS 16
#define DK 64
#define BATCH 2
#define SEQ 2048
#define DMODEL 1024
#define MTOT (BATCH*SEQ)          // 4096
#define NQKV (3*DMODEL)           // 3072
#define NBH  (BATCH*NHEADS)       // 32
#define LOG2E 1.44269504f
#define QSCALE (0.125f * LOG2E)   // fold 1/sqrt(dk) and log2(e) into Q
#define MASKVAL (-10000.0f * LOG2E)

__device__ inline f16x8 ld_f16x8_g(const f16* p) {
  return __builtin_bit_cast(f16x8, *reinterpret_cast<const i32x4*>(p));
}

__device__ inline f16x2 cvt_pk(float a, float b) {
  return __builtin_bit_cast(f16x2, __builtin_amdgcn_cvt_pkrtz(a, b));
}

__device__ inline void gl_lds16(const void* g, void* l) {
  __builtin_amdgcn_global_load_lds(
      (const __attribute__((address_space(1))) unsigned int*)g,
      (__attribute__((address_space(3))) unsigned int*)l, 16, 0, 0);
}

// sigma: swap bits 2,3 (involution) -- the V^T column permutation for 32x32 PV
__device__ inline int sigma_k(int s) {
  return (s & ~12) | ((s & 4) << 1) | ((s & 8) >> 1);
}

// ---------------- fused preprocessing: cvt + 2 transpose-converts ----------------
// blocks [0,4096): x f32->f16 (4/thread); [4096,7168): Wqkv tcvt; [7168,8192): Wout.
__device__ inline void tcvt_tile(float (*tile)[33], const float* __restrict__ in,
                                 f16* __restrict__ out, int K, int N, int k0, int n0) {
  const int t = threadIdx.x, tx = t & 31, ty = t >> 5;
  #pragma unroll
  for (int i = 0; i < 4; ++i)
    tile[ty + 8*i][tx] = in[(size_t)(k0 + ty + 8*i) * N + n0 + tx];
  __syncthreads();
  #pragma unroll
  for (int i = 0; i < 4; ++i)
    out[(size_t)(n0 + ty + 8*i) * K + k0 + tx] = (f16)tile[tx][ty + 8*i];
}

__global__ __launch_bounds__(256) void k_prep(
    const float* __restrict__ x, f16* __restrict__ xh,
    const float* __restrict__ Wqkv, f16* __restrict__ Wqkvt,
    const float* __restrict__ Wout, f16* __restrict__ Woutt)
{
  __shared__ float tile[32][33];
  const int bid = blockIdx.x;
  if (bid < 4096) {
    int i = (bid * 256 + threadIdx.x) * 4;
    float4 v = *reinterpret_cast<const float4*>(x + i);
    f16x4 o = { (f16)v.x, (f16)v.y, (f16)v.z, (f16)v.w };
    *reinterpret_cast<f16x4*>(xh + i) = o;
  } else if (bid < 4096 + 3072) {
    int tl = bid - 4096;                       // 96 n-tiles x 32 k-tiles
    tcvt_tile(tile, Wqkv, Wqkvt, DMODEL, NQKV, (tl / 96) * 32, (tl % 96) * 32);
  } else {
    int tl = bid - 4096 - 3072;                // 32 x 32
    tcvt_tile(tile, Wout, Woutt, DMODEL, DMODEL, (tl / 32) * 32, (tl % 32) * 32);
  }
}

// ------- per-batch prefix-sum of mask -> inv (slot->orig s), cnt. Deterministic. --
__global__ __launch_bounds__(256) void k_scan(const int* __restrict__ mask,
                                              int* __restrict__ inv,
                                              int* __restrict__ cnt) {
  __shared__ int part[256];
  const int b = blockIdx.x;
  const int t = threadIdx.x;
  const int* mp = mask + b * SEQ;
  int* iv = inv + b * SEQ;
  const int base = t * 8;
  int m[8]; int s = 0;
  #pragma unroll
  for (int i = 0; i < 8; ++i) { m[i] = mp[base + i]; s += (m[i] != 0); }
  part[t] = s;
  __syncthreads();
  for (int d = 1; d < 256; d <<= 1) {
    int v = (t >= d) ? part[t - d] : 0;
    __syncthreads();
    part[t] += v;
    __syncthreads();
  }
  int pos = (t == 0) ? 0 : part[t - 1];
  #pragma unroll
  for (int i = 0; i < 8; ++i) {
    if (m[i] != 0) { iv[pos] = base + i; ++pos; }
  }
  if (t == 255) cnt[b] = part[255];
}

// ---------------- Q GEMM: 64x128 tile, full M=4096, N=1024 -----------------------
__global__ __launch_bounds__(256, 2) void k_gemm_q(
    const f16* __restrict__ A, const f16* __restrict__ Bt,
    const float* __restrict__ bias, f16* __restrict__ qo, int K)
{
  __shared__ f16 As[64][64];    // 8 KB
  __shared__ f16 Bs[128][64];   // 16 KB
  const int m0 = blockIdx.y * 64, n0 = blockIdx.x * 128;
  const int t = threadIdx.x;
  const int l = t & 63, w = t >> 6;
  const int lc = l & 15, g = l >> 4;
  const int srow = l >> 3;
  const int ssl  = ((l & 7) ^ srow) * 16;
  const int swz  = (lc & 7) << 4;

  f32x4 acc[4][2] = {};

  for (int kt = 0; kt < K; kt += 64) {
    __syncthreads();
    #pragma unroll
    for (int it = 0; it < 2; ++it) {
      int row = it*32 + w*8 + srow;
      gl_lds16((const char*)(A + (size_t)(m0 + row) * K + kt) + ssl,
               &As[it*32 + w*8][0]);
    }
    #pragma unroll
    for (int it = 0; it < 4; ++it) {
      int row = it*32 + w*8 + srow;
      gl_lds16((const char*)(Bt + (size_t)(n0 + row) * K + kt) + ssl,
               &Bs[it*32 + w*8][0]);
    }
    __syncthreads();

    #pragma unroll
    for (int ks = 0; ks < 64; ks += 32) {
      f16x8 af[4], bf[2];
      #pragma unroll
      for (int i = 0; i < 4; ++i)
        af[i] = *(const f16x8*)((const char*)&As[i*16 + lc][0] + ((ks*2 + g*16) ^ swz));
      #pragma unroll
      for (int j = 0; j < 2; ++j)
        bf[j] = *(const f16x8*)((const char*)&Bs[w*32 + j*16 + lc][0] + ((ks*2 + g*16) ^ swz));
      #pragma unroll
      for (int i = 0; i < 4; ++i)
        #pragma unroll
        for (int j = 0; j < 2; ++j)
          acc[i][j] = __builtin_amdgcn_mfma_f32_16x16x32_f16(af[i], bf[j], acc[i][j], 0, 0, 0);
    }
  }

  #pragma unroll
  for (int i = 0; i < 4; ++i) {
    const int row0 = m0 + i*16 + g*4;
    const int b = row0 >> 11, s0 = row0 & (SEQ - 1);
    #pragma unroll
    for (int j = 0; j < 2; ++j) {
      int col = n0 + w*32 + j*16 + lc;      // [0,1024)
      float bv = bias[col];
      int h = col >> 6, d = col & 63;
      size_t bh = (size_t)(b * NHEADS + h);
      #pragma unroll
      for (int r = 0; r < 4; ++r)
        qo[(bh * SEQ + s0 + r) * DK + d] = (f16)((acc[i][j][r] + bv) * QSCALE);
    }
  }
}

// ---------------- KV GEMM over COMPACTED rows: 64x128 tile -----------------------
// M-space = per-batch compact slots; blocks beyond ceil64(cnt) exit. A-rows
// gathered through inv (per-lane global_load_lds sources). K' written by slot,
// V' at sigma(slot) with f16x4 stores. Pad rows get clamped-row values (finite;
// neutralized in attn by the k<cnt bias and P=0).
__global__ __launch_bounds__(256, 2) void k_gemm_kv(
    const f16* __restrict__ A, const f16* __restrict__ Bt,
    const float* __restrict__ bias, const int* __restrict__ inv,
    const int* __restrict__ cnt,
    f16* __restrict__ ko, f16* __restrict__ vto, int K)
{
  __shared__ f16 As[64][64];    // 8 KB
  __shared__ f16 Bs[128][64];   // 16 KB
  const int m0 = blockIdx.y * 64;           // [0,4096)
  const int n0 = blockIdx.x * 128;          // [0,2048)
  const int b = m0 >> 11, sl0 = m0 & (SEQ - 1);
  const int c = cnt[b];
  if (sl0 >= ((c + 63) & ~63)) return;      // block-uniform early exit

  const int t = threadIdx.x;
  const int l = t & 63, w = t >> 6;
  const int lc = l & 15, g = l >> 4;
  const int srow = l >> 3;
  const int ssl  = ((l & 7) ^ srow) * 16;
  const int swz  = (lc & 7) << 4;

  // gather sources for this lane's 2 staged A-rows (fixed across k-loop)
  int orig[2];
  #pragma unroll
  for (int it = 0; it < 2; ++it) {
    int slot = sl0 + it*32 + w*8 + srow;
    int sidx = (slot < c) ? slot : (c > 0 ? c - 1 : 0);
    orig[it] = inv[b * SEQ + sidx] & (SEQ - 1);
  }

  f32x4 acc[4][2] = {};

  for (int kt = 0; kt < K; kt += 64) {
    __syncthreads();
    #pragma unroll
    for (int it = 0; it < 2; ++it)
      gl_lds16((const char*)(A + ((size_t)(b * SEQ + orig[it])) * K + kt) + ssl,
               &As[it*32 + w*8][0]);
    #pragma unroll
    for (int it = 0; it < 4; ++it) {
      int row = it*32 + w*8 + srow;
      gl_lds16((const char*)(Bt + (size_t)(n0 + row) * K + kt) + ssl,
               &Bs[it*32 + w*8][0]);
    }
    __syncthreads();

    #pragma unroll
    for (int ks = 0; ks < 64; ks += 32) {
      f16x8 af[4], bf[2];
      #pragma unroll
      for (int i = 0; i < 4; ++i)
        af[i] = *(const f16x8*)((const char*)&As[i*16 + lc][0] + ((ks*2 + g*16) ^ swz));
      #pragma unroll
      for (int j = 0; j < 2; ++j)
        bf[j] = *(const f16x8*)((const char*)&Bs[w*32 + j*16 + lc][0] + ((ks*2 + g*16) ^ swz));
      #pragma unroll
      for (int i = 0; i < 4; ++i)
        #pragma unroll
        for (int j = 0; j < 2; ++j)
          acc[i][j] = __builtin_amdgcn_mfma_f32_16x16x32_f16(af[i], bf[j], acc[i][j], 0, 0, 0);
    }
  }

  #pragma unroll
  for (int i = 0; i < 4; ++i) {
    const int slot0 = sl0 + i*16 + g*4;     // 4-aligned; sigma(slot0+r)=sigma(slot0)+r
    #pragma unroll
    for (int j = 0; j < 2; ++j) {
      int colkv = n0 + w*32 + j*16 + lc;    // [0,2048)
      float bv = bias[colkv];
      int kv = colkv >> 10;                 // block-uniform (n0 128-aligned)
      int h = (colkv >> 6) & 15, d = colkv & 63;
      size_t bh = (size_t)(b * NHEADS + h);
      if (kv == 0) {
        #pragma unroll
        for (int r = 0; r < 4; ++r)
          ko[(bh * SEQ + slot0 + r) * DK + d] = (f16)(acc[i][j][r] + bv);
      } else {
        union { f16x2 h2[2]; f16x4 h4; } u;
        u.h2[0] = cvt_pk(acc[i][j][0] + bv, acc[i][j][1] + bv);
        u.h2[1] = cvt_pk(acc[i][j][2] + bv, acc[i][j][3] + bv);
        *(f16x4*)(vto + (bh * DK + d) * SEQ + sigma_k(slot0)) = u.h4;
      }
    }
  }
}

// ---------------- out-proj GEMM: C[M,1024] f32 = A[M,K] * Bt[1024,K]^T + bias -----
__global__ __launch_bounds__(256, 2) void k_gemm_out(
    const f16* __restrict__ A, const f16* __restrict__ Bt,
    const float* __restrict__ bias, float* __restrict__ outf, int N, int K)
{
  __shared__ f16 As[64][64];    // 8 KB
  __shared__ f16 Bs[128][64];   // 16 KB
  const int m0 = blockIdx.y * 64, n0 = blockIdx.x * 128;
  const int t = threadIdx.x;
  const int l = t & 63, w = t >> 6;
  const int lc = l & 15, g = l >> 4;
  const int srow = l >> 3;
  const int ssl  = ((l & 7) ^ srow) * 16;
  const int swz  = (lc & 7) << 4;

  f32x4 acc[4][2] = {};

  for (int kt = 0; kt < K; kt += 64) {
    __syncthreads();
    #pragma unroll
    for (int it = 0; it < 2; ++it) {
      int row = it*32 + w*8 + srow;
      gl_lds16((const char*)(A + (size_t)(m0 + row) * K + kt) + ssl,
               &As[it*32 + w*8][0]);
    }
    #pragma unroll
    for (int it = 0; it < 4; ++it) {
      int row = it*32 + w*8 + srow;
      gl_lds16((const char*)(Bt + (size_t)(n0 + row) * K + kt) + ssl,
               &Bs[it*32 + w*8][0]);
    }
    __syncthreads();

    #pragma unroll
    for (int ks = 0; ks < 64; ks += 32) {
      f16x8 af[4], bf[2];
      #pragma unroll
      for (int i = 0; i < 4; ++i)
        af[i] = *(const f16x8*)((const char*)&As[i*16 + lc][0] + ((ks*2 + g*16) ^ swz));
      #pragma unroll
      for (int j = 0; j < 2; ++j)
        bf[j] = *(const f16x8*)((const char*)&Bs[w*32 + j*16 + lc][0] + ((ks*2 + g*16) ^ swz));
      #pragma unroll
      for (int i = 0; i < 4; ++i)
        #pragma unroll
        for (int j = 0; j < 2; ++j)
          acc[i][j] = __builtin_amdgcn_mfma_f32_16x16x32_f16(af[i], bf[j], acc[i][j], 0, 0, 0);
    }
  }

  #pragma unroll
  for (int i = 0; i < 4; ++i) {
    #pragma unroll
    for (int j = 0; j < 2; ++j) {
      int col = n0 + w*32 + j*16 + lc;
      float bv = bias[col];
      #pragma unroll
      for (int r = 0; r < 4; ++r) {
        int row = m0 + i*16 + g*4 + r;
        outf[(size_t)row * N + col] = acc[i][j][r] + bv;
      }
    }
  }
}

// ---------------- flash attention v10: 32x32 MFMA over COMPACTED keys ------------
__global__ __launch_bounds__(256, 2) void k_attn10(
    const f16* __restrict__ Q, const f16* __restrict__ K,
    const f16* __restrict__ Vt, const int* __restrict__ cnt,
    f16* __restrict__ ctx)
{
  __shared__ f16 Kb[2][32][128];
  __shared__ f16 Vb[2][32][128];

  const int bid = blockIdx.x;
  const int xcd = bid & 7, slot = bid >> 3;        // slot 0..63
  const int bh = xcd * 4 + (slot >> 4);            // 0..31
  const int qb = slot & 15;
  const int b  = bh >> 4, h = bh & (NHEADS - 1);
  const int t = threadIdx.x, l = t & 63, w = t >> 6;
  const int r31 = l & 31, hi = l >> 5;
  const int Rm = r31 & 15;
  const int q0 = qb * 128 + w * 32;

  const int c = cnt[b];
  const int NTc = (c + 63) >> 6;

  const f16* Qp = Q + (size_t)bh * SEQ * DK;
  const f16* Kp = K + (size_t)bh * SEQ * DK;
  const f16* Vp = Vt + (size_t)bh * DK * SEQ;

  f16x8 qf[4];
  #pragma unroll
  for (int ds = 0; ds < 4; ++ds)
    qf[ds] = ld_f16x8_g(Qp + (size_t)(q0 + r31) * DK + ds*16 + hi*8);

  f32x16 o[2] = {};
  float mrow = -3e38f;
  float lsum = 0.f;

  auto stage = [&](int buf, int kt) {
    #pragma unroll
    for (int cc = 0; cc < 2; ++cc) {
      int Rbase = w*8 + cc*4;
      int R = Rbase + (l >> 4);
      int u = (l & 15) ^ (R & 15);
      int off32 = (u >> 3) * 32;
      int byteoff = (u & 7) * 16;
      gl_lds16((const char*)Kp + (size_t)(kt + off32 + R) * (DK*2) + byteoff,
               &Kb[buf][Rbase][0]);
      gl_lds16((const char*)Vp + (size_t)(off32 + R) * (SEQ*2) + (size_t)kt*2 + byteoff,
               &Vb[buf][Rbase][0]);
    }
  };

  stage(0, 0);

  for (int it = 0; it < NTc; ++it) {
    __syncthreads();
    if (it + 1 < NTc) stage((it + 1) & 1, (it + 1) * 64);
    const int kt = it * 64;
    const char* kb = (const char*)&Kb[it & 1][0][0];
    const char* vb = (const char*)&Vb[it & 1][0][0];

    f32x16 p[2];
    if (kt + 64 <= c) {
      #pragma unroll
      for (int T = 0; T < 2; ++T)
        #pragma unroll
        for (int r = 0; r < 16; ++r) p[T][r] = 0.f;
    } else {
      #pragma unroll
      for (int T = 0; T < 2; ++T)
        #pragma unroll
        for (int r = 0; r < 16; ++r) {
          int k = kt + T*32 + 4*hi + (r & 3) + 8*(r >> 2);
          p[T][r] = (k < c) ? 0.f : MASKVAL;
        }
    }

    __builtin_amdgcn_s_setprio(1);
    #pragma unroll
    for (int T = 0; T < 2; ++T)
      #pragma unroll
      for (int ds = 0; ds < 4; ++ds) {
        int slotc = T*8 + ds*2 + hi;
        f16x8 kf = *(const f16x8*)(kb + r31*256 + ((slotc ^ Rm) << 4));
        p[T] = __builtin_amdgcn_mfma_f32_32x32x16_f16(kf, qf[ds], p[T], 0, 0, 0);
      }
    __builtin_amdgcn_s_setprio(0);

    float mx;
    {
      f32x4 t4;
      #pragma unroll
      for (int r = 0; r < 4; ++r)
        t4[r] = fmaxf(fmaxf(p[0][r], p[0][r+4]), fmaxf(p[0][r+8], p[0][r+12]));
      #pragma unroll
      for (int r = 0; r < 4; ++r)
        t4[r] = fmaxf(t4[r], fmaxf(fmaxf(p[1][r], p[1][r+4]), fmaxf(p[1][r+8], p[1][r+12])));
      mx = fmaxf(fmaxf(t4[0], t4[1]), fmaxf(t4[2], t4[3]));
    }
    mx = fmaxf(mx, __shfl_xor(mx, 32));

    if (!__all(mx <= mrow + 8.f)) {
      float nm = fmaxf(mrow, mx);
      float sc = __builtin_amdgcn_exp2f(mrow - nm);
      mrow = nm;
      lsum *= sc;
      #pragma unroll
      for (int dt = 0; dt < 2; ++dt)
        #pragma unroll
        for (int r = 0; r < 16; ++r) o[dt][r] *= sc;
    }

    f16x2 h2[2][8];
    float s0 = 0.f, s1 = 0.f;
    #pragma unroll
    for (int T = 0; T < 2; ++T)
      #pragma unroll
      for (int rp = 0; rp < 8; ++rp) {
        float e0 = __builtin_amdgcn_exp2f(p[T][2*rp]   - mrow);
        float e1 = __builtin_amdgcn_exp2f(p[T][2*rp+1] - mrow);
        s0 += e0; s1 += e1;
        h2[T][rp] = cvt_pk(e0, e1);
      }
    lsum += s0 + s1;

    __builtin_amdgcn_s_setprio(1);
    #pragma unroll
    for (int T = 0; T < 2; ++T)
      #pragma unroll
      for (int half = 0; half < 2; ++half) {
        union { f16x2 a[4]; f16x8 v8; } pu;
        pu.a[0] = h2[T][half*4+0]; pu.a[1] = h2[T][half*4+1];
        pu.a[2] = h2[T][half*4+2]; pu.a[3] = h2[T][half*4+3];
        int m = T*2 + half;
        #pragma unroll
        for (int dt = 0; dt < 2; ++dt) {
          int slotc = dt*8 + m*2 + hi;
          f16x8 vf = *(const f16x8*)(vb + r31*256 + ((slotc ^ Rm) << 4));
          o[dt] = __builtin_amdgcn_mfma_f32_32x32x16_f16(vf, pu.v8, o[dt], 0, 0, 0);
        }
      }
    __builtin_amdgcn_s_setprio(0);
  }

  lsum += __shfl_xor(lsum, 32);
  float inv = 1.f / lsum;
  f16* cp = ctx + (size_t)(b*SEQ + q0 + r31) * DMODEL + h*DK;
  #pragma unroll
  for (int dt = 0; dt < 2; ++dt)
    #pragma unroll
    for (int rq = 0; rq < 4; ++rq) {
      union { f16x2 h2v[2]; f16x4 h4v; } u;
      u.h2v[0] = cvt_pk(o[dt][4*rq+0]*inv, o[dt][4*rq+1]*inv);
      u.h2v[1] = cvt_pk(o[dt][4*rq+2]*inv, o[dt][4*rq+3]*inv);
      *(f16x4*)(cp + dt*32 + 8*rq + 4*hi) = u.h4v;
    }
}

extern "C" void kernel_launch(void* const* d_in, const int* in_sizes, int n_in,
                              void* d_out, int out_size, void* d_ws, size_t ws_size,
                              hipStream_t stream) {
  const float* x    = (const float*)d_in[0];
  const int*   mask = (const int*)d_in[1];
  const float* Wqkv = (const float*)d_in[2];
  const float* bqkv = (const float*)d_in[3];
  const float* Wout = (const float*)d_in[4];
  const float* bout = (const float*)d_in[5];
  float* out = (float*)d_out;

  const size_t SZ_X    = (size_t)MTOT * DMODEL * 2;
  const size_t SZ_WQKV = (size_t)NQKV * DMODEL * 2;
  const size_t SZ_WOUT = (size_t)DMODEL * DMODEL * 2;
  const size_t SZ_QKV  = (size_t)BATCH * NHEADS * SEQ * DK * 2;
  const size_t SZ_INV  = (size_t)MTOT * 4;    // inv: 4096 ints
  const size_t SZ_CNT  = 256;
  const size_t NEED = SZ_X + SZ_WQKV + SZ_WOUT + 3*SZ_QKV + SZ_X + SZ_INV + SZ_CNT;
  if (ws_size < NEED) return;

  char* p = (char*)d_ws;
  f16* xh    = (f16*)p; p += SZ_X;
  f16* Wqkvt = (f16*)p; p += SZ_WQKV;
  f16* Woutt = (f16*)p; p += SZ_WOUT;
  f16* Qh    = (f16*)p; p += SZ_QKV;
  f16* Kh    = (f16*)p; p += SZ_QKV;
  f16* Vth   = (f16*)p; p += SZ_QKV;
  f16* ctx   = (f16*)p; p += SZ_X;
  int* inv   = (int*)p; p += SZ_INV;
  int* cnt   = (int*)p; p += SZ_CNT;

  k_prep<<<4096 + 3072 + 1024, 256, 0, stream>>>(x, xh, Wqkv, Wqkvt, Wout, Woutt);
  k_scan<<<BATCH, 256, 0, stream>>>(mask, inv, cnt);

  k_gemm_q<<<dim3(DMODEL/128, MTOT/64), 256, 0, stream>>>(
      xh, Wqkvt, bqkv, Qh, DMODEL);
  k_gemm_kv<<<dim3(2048/128, MTOT/64), 256, 0, stream>>>(
      xh, Wqkvt + (size_t)DMODEL*DMODEL, bqkv + DMODEL, inv, cnt, Kh, Vth, DMODEL);

  k_attn10<<<32 * 16, 256, 0, stream>>>(Qh, Kh, Vth, cnt, ctx);

  k_gemm_out<<<dim3(DMODEL/128, MTOT/64), 256, 0, stream>>>(
      ctx, Woutt, bout, out, DMODEL, DMODEL);
}

// Round 16
// 97.728 us; speedup vs baseline: 1.4875x; 1.0643x over previous
//
#include <hip/hip_runtime.h>

typedef _Float16 f16;
typedef _Float16 f16x2 __attribute__((ext_vector_type(2)));
typedef _Float16 f16x4 __attribute__((ext_vector_type(4)));
typedef _Float16 f16x8 __attribute__((ext_vector_type(8)));
typedef float    f32x4 __attribute__((ext_vector_type(4)));
typedef float    f32x16 __attribute__((ext_vector_type(16)));
typedef int      i32x4 __attribute__((ext_vector_type(4)));

#define NHEADS 16
#define DK 64
#define BATCH 2
#define SEQ 2048
#define DMODEL 1024
#define MTOT (BATCH*SEQ)          // 4096
#define NQKV (3*DMODEL)           // 3072
#define NBH  (BATCH*NHEADS)       // 32
#define LOG2E 1.44269504f
#define QSCALE (0.125f * LOG2E)   // fold 1/sqrt(dk) and log2(e) into Q
#define MASKVAL (-10000.0f * LOG2E)

__device__ inline f16x8 ld_f16x8_g(const f16* p) {
  return __builtin_bit_cast(f16x8, *reinterpret_cast<const i32x4*>(p));
}

__device__ inline f16x2 cvt_pk(float a, float b) {
  return __builtin_bit_cast(f16x2, __builtin_amdgcn_cvt_pkrtz(a, b));
}

__device__ inline void gl_lds16(const void* g, void* l) {
  __builtin_amdgcn_global_load_lds(
      (const __attribute__((address_space(1))) unsigned int*)g,
      (__attribute__((address_space(3))) unsigned int*)l, 16, 0, 0);
}

// sigma: swap bits 2,3 (involution) -- the V^T column permutation for 32x32 PV
__device__ inline int sigma_k(int s) {
  return (s & ~12) | ((s & 4) << 1) | ((s & 8) >> 1);
}

// ---------------- fused preprocessing: cvt + 2 tcvts + mask scan -----------------
// blocks [0,4096): x f32->f16; [4096,7168): Wqkv tcvt; [7168,8192): Wout tcvt;
// [8192,8194): per-batch mask prefix-scan -> inv (slot->s), cnt.
__device__ inline void tcvt_tile(float (*tile)[33], const float* __restrict__ in,
                                 f16* __restrict__ out, int K, int N, int k0, int n0) {
  const int t = threadIdx.x, tx = t & 31, ty = t >> 5;
  #pragma unroll
  for (int i = 0; i < 4; ++i)
    tile[ty + 8*i][tx] = in[(size_t)(k0 + ty + 8*i) * N + n0 + tx];
  __syncthreads();
  #pragma unroll
  for (int i = 0; i < 4; ++i)
    out[(size_t)(n0 + ty + 8*i) * K + k0 + tx] = (f16)tile[tx][ty + 8*i];
}

__global__ __launch_bounds__(256) void k_prep(
    const float* __restrict__ x, f16* __restrict__ xh,
    const float* __restrict__ Wqkv, f16* __restrict__ Wqkvt,
    const float* __restrict__ Wout, f16* __restrict__ Woutt,
    const int* __restrict__ mask, int* __restrict__ inv, int* __restrict__ cnt)
{
  __shared__ float tile[32][33];
  __shared__ int part[256];
  const int bid = blockIdx.x;
  const int t = threadIdx.x;
  if (bid < 4096) {
    int i = (bid * 256 + t) * 4;
    float4 v = *reinterpret_cast<const float4*>(x + i);
    f16x4 o = { (f16)v.x, (f16)v.y, (f16)v.z, (f16)v.w };
    *reinterpret_cast<f16x4*>(xh + i) = o;
  } else if (bid < 4096 + 3072) {
    int tl = bid - 4096;                       // 96 n-tiles x 32 k-tiles
    tcvt_tile(tile, Wqkv, Wqkvt, DMODEL, NQKV, (tl / 96) * 32, (tl % 96) * 32);
  } else if (bid < 8192) {
    int tl = bid - 4096 - 3072;                // 32 x 32
    tcvt_tile(tile, Wout, Woutt, DMODEL, DMODEL, (tl / 32) * 32, (tl % 32) * 32);
  } else {
    // deterministic per-batch scan
    const int b = bid - 8192;
    const int* mp = mask + b * SEQ;
    int* iv = inv + b * SEQ;
    const int base = t * 8;
    int m[8]; int s = 0;
    #pragma unroll
    for (int i = 0; i < 8; ++i) { m[i] = mp[base + i]; s += (m[i] != 0); }
    part[t] = s;
    __syncthreads();
    for (int d = 1; d < 256; d <<= 1) {
      int v = (t >= d) ? part[t - d] : 0;
      __syncthreads();
      part[t] += v;
      __syncthreads();
    }
    int pos = (t == 0) ? 0 : part[t - 1];
    #pragma unroll
    for (int i = 0; i < 8; ++i) {
      if (m[i] != 0) { iv[pos] = base + i; ++pos; }
    }
    if (t == 255) cnt[b] = part[255];
  }
}

// ---------------- merged QKV GEMM: Q-part (512 blocks) + KV-part (1024 blocks) ---
// Both parts share the 64x128-tile main loop; only the per-lane A-row offsets
// (identity vs inv-gather) and the epilogue differ (block-uniform). KV blocks
// beyond ceil64(cnt) exit immediately, freeing slots for Q blocks -> overlap.
__global__ __launch_bounds__(256, 2) void k_gemm_qkv2(
    const f16* __restrict__ A, const f16* __restrict__ Bt,
    const float* __restrict__ bias, const int* __restrict__ inv,
    const int* __restrict__ cnt,
    f16* __restrict__ qo, f16* __restrict__ ko, f16* __restrict__ vto, int K)
{
  __shared__ f16 As[64][64];    // 8 KB
  __shared__ f16 Bs[128][64];   // 16 KB
  const int bid = blockIdx.x;
  const bool isQ = bid < 512;

  const int t = threadIdx.x;
  const int l = t & 63, w = t >> 6;
  const int lc = l & 15, g = l >> 4;
  const int srow = l >> 3;
  const int ssl  = ((l & 7) ^ srow) * 16;
  const int swz  = (lc & 7) << 4;

  int m0, n0, b = 0, c = 0;
  const f16* Btp;
  const float* biasp;
  size_t aoff[2];
  if (isQ) {
    n0 = (bid & 7) * 128;  m0 = (bid >> 3) * 64;
    Btp = Bt;  biasp = bias;
    #pragma unroll
    for (int it = 0; it < 2; ++it)
      aoff[it] = (size_t)(m0 + it*32 + w*8 + srow) * K;
  } else {
    const int idx = bid - 512;
    n0 = (idx & 15) * 128;  m0 = (idx >> 4) * 64;
    b = m0 >> 11;
    const int sl0 = m0 & (SEQ - 1);
    c = cnt[b];
    if (sl0 >= ((c + 63) & ~63)) return;    // block-uniform early exit
    Btp = Bt + (size_t)DMODEL * DMODEL;     // K/V weight rows
    biasp = bias + DMODEL;
    #pragma unroll
    for (int it = 0; it < 2; ++it) {
      int slot = sl0 + it*32 + w*8 + srow;
      int sidx = (slot < c) ? slot : (c > 0 ? c - 1 : 0);
      aoff[it] = (size_t)(b * SEQ + (inv[b * SEQ + sidx] & (SEQ - 1))) * K;
    }
  }

  f32x4 acc[4][2] = {};

  for (int kt = 0; kt < K; kt += 64) {
    __syncthreads();
    #pragma unroll
    for (int it = 0; it < 2; ++it)
      gl_lds16((const char*)(A + aoff[it] + kt) + ssl, &As[it*32 + w*8][0]);
    #pragma unroll
    for (int it = 0; it < 4; ++it) {
      int row = it*32 + w*8 + srow;
      gl_lds16((const char*)(Btp + (size_t)(n0 + row) * K + kt) + ssl,
               &Bs[it*32 + w*8][0]);
    }
    __syncthreads();

    #pragma unroll
    for (int ks = 0; ks < 64; ks += 32) {
      f16x8 af[4], bf[2];
      #pragma unroll
      for (int i = 0; i < 4; ++i)
        af[i] = *(const f16x8*)((const char*)&As[i*16 + lc][0] + ((ks*2 + g*16) ^ swz));
      #pragma unroll
      for (int j = 0; j < 2; ++j)
        bf[j] = *(const f16x8*)((const char*)&Bs[w*32 + j*16 + lc][0] + ((ks*2 + g*16) ^ swz));
      #pragma unroll
      for (int i = 0; i < 4; ++i)
        #pragma unroll
        for (int j = 0; j < 2; ++j)
          acc[i][j] = __builtin_amdgcn_mfma_f32_16x16x32_f16(af[i], bf[j], acc[i][j], 0, 0, 0);
    }
  }

  if (isQ) {
    #pragma unroll
    for (int i = 0; i < 4; ++i) {
      const int row0 = m0 + i*16 + g*4;
      const int qb = row0 >> 11, s0 = row0 & (SEQ - 1);
      #pragma unroll
      for (int j = 0; j < 2; ++j) {
        int col = n0 + w*32 + j*16 + lc;      // [0,1024)
        float bv = biasp[col];
        int h = col >> 6, d = col & 63;
        size_t bh = (size_t)(qb * NHEADS + h);
        #pragma unroll
        for (int r = 0; r < 4; ++r)
          qo[(bh * SEQ + s0 + r) * DK + d] = (f16)((acc[i][j][r] + bv) * QSCALE);
      }
    }
  } else {
    const int sl0 = m0 & (SEQ - 1);
    #pragma unroll
    for (int i = 0; i < 4; ++i) {
      const int slot0 = sl0 + i*16 + g*4;     // 4-aligned; sigma(slot0)+r contiguous
      #pragma unroll
      for (int j = 0; j < 2; ++j) {
        int colkv = n0 + w*32 + j*16 + lc;    // [0,2048)
        float bv = biasp[colkv];
        int kv = colkv >> 10;                 // block-uniform
        int h = (colkv >> 6) & 15, d = colkv & 63;
        size_t bh = (size_t)(b * NHEADS + h);
        if (kv == 0) {
          #pragma unroll
          for (int r = 0; r < 4; ++r)
            ko[(bh * SEQ + slot0 + r) * DK + d] = (f16)(acc[i][j][r] + bv);
        } else {
          union { f16x2 h2[2]; f16x4 h4; } u;
          u.h2[0] = cvt_pk(acc[i][j][0] + bv, acc[i][j][1] + bv);
          u.h2[1] = cvt_pk(acc[i][j][2] + bv, acc[i][j][3] + bv);
          *(f16x4*)(vto + (bh * DK + d) * SEQ + sigma_k(slot0)) = u.h4;
        }
      }
    }
  }
}

// ---------------- out-proj GEMM: C[M,1024] f32 = A[M,K] * Bt[1024,K]^T + bias -----
__global__ __launch_bounds__(256, 2) void k_gemm_out(
    const f16* __restrict__ A, const f16* __restrict__ Bt,
    const float* __restrict__ bias, float* __restrict__ outf, int N, int K)
{
  __shared__ f16 As[64][64];    // 8 KB
  __shared__ f16 Bs[128][64];   // 16 KB
  const int m0 = blockIdx.y * 64, n0 = blockIdx.x * 128;
  const int t = threadIdx.x;
  const int l = t & 63, w = t >> 6;
  const int lc = l & 15, g = l >> 4;
  const int srow = l >> 3;
  const int ssl  = ((l & 7) ^ srow) * 16;
  const int swz  = (lc & 7) << 4;

  f32x4 acc[4][2] = {};

  for (int kt = 0; kt < K; kt += 64) {
    __syncthreads();
    #pragma unroll
    for (int it = 0; it < 2; ++it) {
      int row = it*32 + w*8 + srow;
      gl_lds16((const char*)(A + (size_t)(m0 + row) * K + kt) + ssl,
               &As[it*32 + w*8][0]);
    }
    #pragma unroll
    for (int it = 0; it < 4; ++it) {
      int row = it*32 + w*8 + srow;
      gl_lds16((const char*)(Bt + (size_t)(n0 + row) * K + kt) + ssl,
               &Bs[it*32 + w*8][0]);
    }
    __syncthreads();

    #pragma unroll
    for (int ks = 0; ks < 64; ks += 32) {
      f16x8 af[4], bf[2];
      #pragma unroll
      for (int i = 0; i < 4; ++i)
        af[i] = *(const f16x8*)((const char*)&As[i*16 + lc][0] + ((ks*2 + g*16) ^ swz));
      #pragma unroll
      for (int j = 0; j < 2; ++j)
        bf[j] = *(const f16x8*)((const char*)&Bs[w*32 + j*16 + lc][0] + ((ks*2 + g*16) ^ swz));
      #pragma unroll
      for (int i = 0; i < 4; ++i)
        #pragma unroll
        for (int j = 0; j < 2; ++j)
          acc[i][j] = __builtin_amdgcn_mfma_f32_16x16x32_f16(af[i], bf[j], acc[i][j], 0, 0, 0);
    }
  }

  #pragma unroll
  for (int i = 0; i < 4; ++i) {
    #pragma unroll
    for (int j = 0; j < 2; ++j) {
      int col = n0 + w*32 + j*16 + lc;
      float bv = bias[col];
      #pragma unroll
      for (int r = 0; r < 4; ++r) {
        int row = m0 + i*16 + g*4 + r;
        outf[(size_t)row * N + col] = acc[i][j][r] + bv;
      }
    }
  }
}

// ---------------- flash attention v10: 32x32 MFMA over COMPACTED keys ------------
__global__ __launch_bounds__(256, 2) void k_attn10(
    const f16* __restrict__ Q, const f16* __restrict__ K,
    const f16* __restrict__ Vt, const int* __restrict__ cnt,
    f16* __restrict__ ctx)
{
  __shared__ f16 Kb[2][32][128];
  __shared__ f16 Vb[2][32][128];

  const int bid = blockIdx.x;
  const int xcd = bid & 7, slot = bid >> 3;        // slot 0..63
  const int bh = xcd * 4 + (slot >> 4);            // 0..31
  const int qb = slot & 15;
  const int b  = bh >> 4, h = bh & (NHEADS - 1);
  const int t = threadIdx.x, l = t & 63, w = t >> 6;
  const int r31 = l & 31, hi = l >> 5;
  const int Rm = r31 & 15;
  const int q0 = qb * 128 + w * 32;

  const int c = cnt[b];
  const int NTc = (c + 63) >> 6;

  const f16* Qp = Q + (size_t)bh * SEQ * DK;
  const f16* Kp = K + (size_t)bh * SEQ * DK;
  const f16* Vp = Vt + (size_t)bh * DK * SEQ;

  f16x8 qf[4];
  #pragma unroll
  for (int ds = 0; ds < 4; ++ds)
    qf[ds] = ld_f16x8_g(Qp + (size_t)(q0 + r31) * DK + ds*16 + hi*8);

  f32x16 o[2] = {};
  float mrow = -3e38f;
  float lsum = 0.f;

  auto stage = [&](int buf, int kt) {
    #pragma unroll
    for (int cc = 0; cc < 2; ++cc) {
      int Rbase = w*8 + cc*4;
      int R = Rbase + (l >> 4);
      int u = (l & 15) ^ (R & 15);
      int off32 = (u >> 3) * 32;
      int byteoff = (u & 7) * 16;
      gl_lds16((const char*)Kp + (size_t)(kt + off32 + R) * (DK*2) + byteoff,
               &Kb[buf][Rbase][0]);
      gl_lds16((const char*)Vp + (size_t)(off32 + R) * (SEQ*2) + (size_t)kt*2 + byteoff,
               &Vb[buf][Rbase][0]);
    }
  };

  stage(0, 0);

  for (int it = 0; it < NTc; ++it) {
    __syncthreads();
    if (it + 1 < NTc) stage((it + 1) & 1, (it + 1) * 64);
    const int kt = it * 64;
    const char* kb = (const char*)&Kb[it & 1][0][0];
    const char* vb = (const char*)&Vb[it & 1][0][0];

    f32x16 p[2];
    if (kt + 64 <= c) {
      #pragma unroll
      for (int T = 0; T < 2; ++T)
        #pragma unroll
        for (int r = 0; r < 16; ++r) p[T][r] = 0.f;
    } else {
      #pragma unroll
      for (int T = 0; T < 2; ++T)
        #pragma unroll
        for (int r = 0; r < 16; ++r) {
          int k = kt + T*32 + 4*hi + (r & 3) + 8*(r >> 2);
          p[T][r] = (k < c) ? 0.f : MASKVAL;
        }
    }

    __builtin_amdgcn_s_setprio(1);
    #pragma unroll
    for (int T = 0; T < 2; ++T)
      #pragma unroll
      for (int ds = 0; ds < 4; ++ds) {
        int slotc = T*8 + ds*2 + hi;
        f16x8 kf = *(const f16x8*)(kb + r31*256 + ((slotc ^ Rm) << 4));
        p[T] = __builtin_amdgcn_mfma_f32_32x32x16_f16(kf, qf[ds], p[T], 0, 0, 0);
      }
    __builtin_amdgcn_s_setprio(0);

    float mx;
    {
      f32x4 t4;
      #pragma unroll
      for (int r = 0; r < 4; ++r)
        t4[r] = fmaxf(fmaxf(p[0][r], p[0][r+4]), fmaxf(p[0][r+8], p[0][r+12]));
      #pragma unroll
      for (int r = 0; r < 4; ++r)
        t4[r] = fmaxf(t4[r], fmaxf(fmaxf(p[1][r], p[1][r+4]), fmaxf(p[1][r+8], p[1][r+12])));
      mx = fmaxf(fmaxf(t4[0], t4[1]), fmaxf(t4[2], t4[3]));
    }
    mx = fmaxf(mx, __shfl_xor(mx, 32));

    if (!__all(mx <= mrow + 8.f)) {
      float nm = fmaxf(mrow, mx);
      float sc = __builtin_amdgcn_exp2f(mrow - nm);
      mrow = nm;
      lsum *= sc;
      #pragma unroll
      for (int dt = 0; dt < 2; ++dt)
        #pragma unroll
        for (int r = 0; r < 16; ++r) o[dt][r] *= sc;
    }

    f16x2 h2[2][8];
    float s0 = 0.f, s1 = 0.f;
    #pragma unroll
    for (int T = 0; T < 2; ++T)
      #pragma unroll
      for (int rp = 0; rp < 8; ++rp) {
        float e0 = __builtin_amdgcn_exp2f(p[T][2*rp]   - mrow);
        float e1 = __builtin_amdgcn_exp2f(p[T][2*rp+1] - mrow);
        s0 += e0; s1 += e1;
        h2[T][rp] = cvt_pk(e0, e1);
      }
    lsum += s0 + s1;

    __builtin_amdgcn_s_setprio(1);
    #pragma unroll
    for (int T = 0; T < 2; ++T)
      #pragma unroll
      for (int half = 0; half < 2; ++half) {
        union { f16x2 a[4]; f16x8 v8; } pu;
        pu.a[0] = h2[T][half*4+0]; pu.a[1] = h2[T][half*4+1];
        pu.a[2] = h2[T][half*4+2]; pu.a[3] = h2[T][half*4+3];
        int m = T*2 + half;
        #pragma unroll
        for (int dt = 0; dt < 2; ++dt) {
          int slotc = dt*8 + m*2 + hi;
          f16x8 vf = *(const f16x8*)(vb + r31*256 + ((slotc ^ Rm) << 4));
          o[dt] = __builtin_amdgcn_mfma_f32_32x32x16_f16(vf, pu.v8, o[dt], 0, 0, 0);
        }
      }
    __builtin_amdgcn_s_setprio(0);
  }

  lsum += __shfl_xor(lsum, 32);
  float inv = 1.f / lsum;
  f16* cp = ctx + (size_t)(b*SEQ + q0 + r31) * DMODEL + h*DK;
  #pragma unroll
  for (int dt = 0; dt < 2; ++dt)
    #pragma unroll
    for (int rq = 0; rq < 4; ++rq) {
      union { f16x2 h2v[2]; f16x4 h4v; } u;
      u.h2v[0] = cvt_pk(o[dt][4*rq+0]*inv, o[dt][4*rq+1]*inv);
      u.h2v[1] = cvt_pk(o[dt][4*rq+2]*inv, o[dt][4*rq+3]*inv);
      *(f16x4*)(cp + dt*32 + 8*rq + 4*hi) = u.h4v;
    }
}

extern "C" void kernel_launch(void* const* d_in, const int* in_sizes, int n_in,
                              void* d_out, int out_size, void* d_ws, size_t ws_size,
                              hipStream_t stream) {
  const float* x    = (const float*)d_in[0];
  const int*   mask = (const int*)d_in[1];
  const float* Wqkv = (const float*)d_in[2];
  const float* bqkv = (const float*)d_in[3];
  const float* Wout = (const float*)d_in[4];
  const float* bout = (const float*)d_in[5];
  float* out = (float*)d_out;

  const size_t SZ_X    = (size_t)MTOT * DMODEL * 2;
  const size_t SZ_WQKV = (size_t)NQKV * DMODEL * 2;
  const size_t SZ_WOUT = (size_t)DMODEL * DMODEL * 2;
  const size_t SZ_QKV  = (size_t)BATCH * NHEADS * SEQ * DK * 2;
  const size_t SZ_INV  = (size_t)MTOT * 4;    // inv: 4096 ints
  const size_t SZ_CNT  = 256;
  const size_t NEED = SZ_X + SZ_WQKV + SZ_WOUT + 3*SZ_QKV + SZ_X + SZ_INV + SZ_CNT;
  if (ws_size < NEED) return;

  char* p = (char*)d_ws;
  f16* xh    = (f16*)p; p += SZ_X;
  f16* Wqkvt = (f16*)p; p += SZ_WQKV;
  f16* Woutt = (f16*)p; p += SZ_WOUT;
  f16* Qh    = (f16*)p; p += SZ_QKV;
  f16* Kh    = (f16*)p; p += SZ_QKV;
  f16* Vth   = (f16*)p; p += SZ_QKV;
  f16* ctx   = (f16*)p; p += SZ_X;
  int* inv   = (int*)p; p += SZ_INV;
  int* cnt   = (int*)p; p += SZ_CNT;

  k_prep<<<4096 + 3072 + 1024 + BATCH, 256, 0, stream>>>(
      x, xh, Wqkv, Wqkvt, Wout, Woutt, mask, inv, cnt);

  k_gemm_qkv2<<<512 + 1024, 256, 0, stream>>>(
      xh, Wqkvt, bqkv, inv, cnt, Qh, Kh, Vth, DMODEL);

  k_attn10<<<32 * 16, 256, 0, stream>>>(Qh, Kh, Vth, cnt, ctx);

  k_gemm_out<<<dim3(DMODEL/128, MTOT/64), 256, 0, stream>>>(
      ctx, Woutt, bout, out, DMODEL, DMODEL);
}

// Round 17
// 96.226 us; speedup vs baseline: 1.5107x; 1.0156x over previous
//
#include <hip/hip_runtime.h>

typedef _Float16 f16;
typedef _Float16 f16x2 __attribute__((ext_vector_type(2)));
typedef _Float16 f16x4 __attribute__((ext_vector_type(4)));
typedef _Float16 f16x8 __attribute__((ext_vector_type(8)));
typedef float    f32x4 __attribute__((ext_vector_type(4)));
typedef float    f32x16 __attribute__((ext_vector_type(16)));
typedef int      i32x4 __attribute__((ext_vector_type(4)));

#define NHEADS 16
#define DK 64
#define BATCH 2
#define SEQ 2048
#define DMODEL 1024
#define MTOT (BATCH*SEQ)          // 4096
#define NQKV (3*DMODEL)           // 3072
#define NBH  (BATCH*NHEADS)       // 32
#define LOG2E 1.44269504f
#define QSCALE (0.125f * LOG2E)   // fold 1/sqrt(dk) and log2(e) into Q
#define MASKVAL (-10000.0f * LOG2E)

__device__ inline f16x8 ld_f16x8_g(const f16* p) {
  return __builtin_bit_cast(f16x8, *reinterpret_cast<const i32x4*>(p));
}

__device__ inline f16x2 cvt_pk(float a, float b) {
  return __builtin_bit_cast(f16x2, __builtin_amdgcn_cvt_pkrtz(a, b));
}

__device__ inline void gl_lds16(const void* g, void* l) {
  __builtin_amdgcn_global_load_lds(
      (const __attribute__((address_space(1))) unsigned int*)g,
      (__attribute__((address_space(3))) unsigned int*)l, 16, 0, 0);
}

// sigma: swap bits 2,3 (involution) -- the V^T column permutation for 32x32 PV
__device__ inline int sigma_k(int s) {
  return (s & ~12) | ((s & 4) << 1) | ((s & 8) >> 1);
}

// ---------------- fused preprocessing: cvt + 2 tcvts + mask scan -----------------
// blocks [0,4096): x f32->f16; [4096,7168): Wqkv tcvt; [7168,8192): Wout tcvt;
// [8192,8194): per-batch mask prefix-scan -> inv (slot->s), cnt.
// tcvt: float4 reads, one pass per side, 2-way LDS conflicts (free), f16x4 stores.
__device__ inline void tcvt_tile(float (*tile)[33], const float* __restrict__ in,
                                 f16* __restrict__ out, int K, int N, int k0, int n0) {
  const int t = threadIdx.x, j = t & 7, ty = t >> 3;   // j: 4-col group, ty: row 0..31
  float4 v = *reinterpret_cast<const float4*>(in + (size_t)(k0 + ty) * N + n0 + j*4);
  tile[ty][j*4+0] = v.x; tile[ty][j*4+1] = v.y;
  tile[ty][j*4+2] = v.z; tile[ty][j*4+3] = v.w;
  __syncthreads();
  union { f16x2 h2[2]; f16x4 h4; } u;
  u.h2[0] = cvt_pk(tile[j*4+0][ty], tile[j*4+1][ty]);
  u.h2[1] = cvt_pk(tile[j*4+2][ty], tile[j*4+3][ty]);
  *(f16x4*)(out + (size_t)(n0 + ty) * K + k0 + j*4) = u.h4;
}

__global__ __launch_bounds__(256) void k_prep(
    const float* __restrict__ x, f16* __restrict__ xh,
    const float* __restrict__ Wqkv, f16* __restrict__ Wqkvt,
    const float* __restrict__ Wout, f16* __restrict__ Woutt,
    const int* __restrict__ mask, int* __restrict__ inv, int* __restrict__ cnt)
{
  __shared__ float tile[32][33];
  __shared__ int part[256];
  const int bid = blockIdx.x;
  const int t = threadIdx.x;
  if (bid < 4096) {
    int i = (bid * 256 + t) * 4;
    float4 v = *reinterpret_cast<const float4*>(x + i);
    f16x4 o = { (f16)v.x, (f16)v.y, (f16)v.z, (f16)v.w };
    *reinterpret_cast<f16x4*>(xh + i) = o;
  } else if (bid < 4096 + 3072) {
    int tl = bid - 4096;                       // 96 n-tiles x 32 k-tiles
    tcvt_tile(tile, Wqkv, Wqkvt, DMODEL, NQKV, (tl / 96) * 32, (tl % 96) * 32);
  } else if (bid < 8192) {
    int tl = bid - 4096 - 3072;                // 32 x 32
    tcvt_tile(tile, Wout, Woutt, DMODEL, DMODEL, (tl / 32) * 32, (tl % 32) * 32);
  } else {
    // deterministic per-batch scan
    const int b = bid - 8192;
    const int* mp = mask + b * SEQ;
    int* iv = inv + b * SEQ;
    const int base = t * 8;
    int m[8]; int s = 0;
    #pragma unroll
    for (int i = 0; i < 8; ++i) { m[i] = mp[base + i]; s += (m[i] != 0); }
    part[t] = s;
    __syncthreads();
    for (int d = 1; d < 256; d <<= 1) {
      int v = (t >= d) ? part[t - d] : 0;
      __syncthreads();
      part[t] += v;
      __syncthreads();
    }
    int pos = (t == 0) ? 0 : part[t - 1];
    #pragma unroll
    for (int i = 0; i < 8; ++i) {
      if (m[i] != 0) { iv[pos] = base + i; ++pos; }
    }
    if (t == 255) cnt[b] = part[255];
  }
}

// ---------------- merged QKV GEMM, DOUBLE-BUFFERED 64x128 tile -------------------
// Q-part (512 blocks) + KV-part (1024 blocks, compact-row gather, early exit).
// LDS 48 KB -> still 2 blocks/CU; one barrier per K-step, loads hide under MFMA.
__global__ __launch_bounds__(256, 2) void k_gemm_qkv2(
    const f16* __restrict__ A, const f16* __restrict__ Bt,
    const float* __restrict__ bias, const int* __restrict__ inv,
    const int* __restrict__ cnt,
    f16* __restrict__ qo, f16* __restrict__ ko, f16* __restrict__ vto, int K)
{
  __shared__ f16 As[2][64][64];    // 16 KB
  __shared__ f16 Bs[2][128][64];   // 32 KB
  const int bid = blockIdx.x;
  const bool isQ = bid < 512;

  const int t = threadIdx.x;
  const int l = t & 63, w = t >> 6;
  const int lc = l & 15, g = l >> 4;
  const int srow = l >> 3;
  const int ssl  = ((l & 7) ^ srow) * 16;
  const int swz  = (lc & 7) << 4;

  int m0, n0, b = 0, c = 0;
  const f16* Btp;
  const float* biasp;
  size_t aoff[2];
  if (isQ) {
    n0 = (bid & 7) * 128;  m0 = (bid >> 3) * 64;
    Btp = Bt;  biasp = bias;
    #pragma unroll
    for (int it = 0; it < 2; ++it)
      aoff[it] = (size_t)(m0 + it*32 + w*8 + srow) * K;
  } else {
    const int idx = bid - 512;
    n0 = (idx & 15) * 128;  m0 = (idx >> 4) * 64;
    b = m0 >> 11;
    const int sl0 = m0 & (SEQ - 1);
    c = cnt[b];
    if (sl0 >= ((c + 63) & ~63)) return;    // block-uniform early exit
    Btp = Bt + (size_t)DMODEL * DMODEL;     // K/V weight rows
    biasp = bias + DMODEL;
    #pragma unroll
    for (int it = 0; it < 2; ++it) {
      int slot = sl0 + it*32 + w*8 + srow;
      int sidx = (slot < c) ? slot : (c > 0 ? c - 1 : 0);
      aoff[it] = (size_t)(b * SEQ + (inv[b * SEQ + sidx] & (SEQ - 1))) * K;
    }
  }

  auto stage = [&](int buf, int kt) {
    #pragma unroll
    for (int it = 0; it < 2; ++it)
      gl_lds16((const char*)(A + aoff[it] + kt) + ssl, &As[buf][it*32 + w*8][0]);
    #pragma unroll
    for (int it = 0; it < 4; ++it) {
      int row = it*32 + w*8 + srow;
      gl_lds16((const char*)(Btp + (size_t)(n0 + row) * K + kt) + ssl,
               &Bs[buf][it*32 + w*8][0]);
    }
  };

  f32x4 acc[4][2] = {};
  const int NTk = K >> 6;
  stage(0, 0);

  for (int ti = 0; ti < NTk; ++ti) {
    __syncthreads();                          // stage(ti) complete
    if (ti + 1 < NTk) stage((ti + 1) & 1, (ti + 1) * 64);
    const char* abase = (const char*)&As[ti & 1][0][0];
    const char* bbase = (const char*)&Bs[ti & 1][0][0];
    #pragma unroll
    for (int ks = 0; ks < 64; ks += 32) {
      f16x8 af[4], bf[2];
      #pragma unroll
      for (int i = 0; i < 4; ++i)
        af[i] = *(const f16x8*)(abase + (i*16 + lc)*128 + ((ks*2 + g*16) ^ swz));
      #pragma unroll
      for (int j = 0; j < 2; ++j)
        bf[j] = *(const f16x8*)(bbase + (w*32 + j*16 + lc)*128 + ((ks*2 + g*16) ^ swz));
      #pragma unroll
      for (int i = 0; i < 4; ++i)
        #pragma unroll
        for (int j = 0; j < 2; ++j)
          acc[i][j] = __builtin_amdgcn_mfma_f32_16x16x32_f16(af[i], bf[j], acc[i][j], 0, 0, 0);
    }
  }

  if (isQ) {
    #pragma unroll
    for (int i = 0; i < 4; ++i) {
      const int row0 = m0 + i*16 + g*4;
      const int qb = row0 >> 11, s0 = row0 & (SEQ - 1);
      #pragma unroll
      for (int j = 0; j < 2; ++j) {
        int col = n0 + w*32 + j*16 + lc;      // [0,1024)
        float bv = biasp[col];
        int h = col >> 6, d = col & 63;
        size_t bh = (size_t)(qb * NHEADS + h);
        #pragma unroll
        for (int r = 0; r < 4; ++r)
          qo[(bh * SEQ + s0 + r) * DK + d] = (f16)((acc[i][j][r] + bv) * QSCALE);
      }
    }
  } else {
    const int sl0 = m0 & (SEQ - 1);
    #pragma unroll
    for (int i = 0; i < 4; ++i) {
      const int slot0 = sl0 + i*16 + g*4;     // 4-aligned; sigma(slot0)+r contiguous
      #pragma unroll
      for (int j = 0; j < 2; ++j) {
        int colkv = n0 + w*32 + j*16 + lc;    // [0,2048)
        float bv = biasp[colkv];
        int kv = colkv >> 10;                 // block-uniform
        int h = (colkv >> 6) & 15, d = colkv & 63;
        size_t bh = (size_t)(b * NHEADS + h);
        if (kv == 0) {
          #pragma unroll
          for (int r = 0; r < 4; ++r)
            ko[(bh * SEQ + slot0 + r) * DK + d] = (f16)(acc[i][j][r] + bv);
        } else {
          union { f16x2 h2[2]; f16x4 h4; } u;
          u.h2[0] = cvt_pk(acc[i][j][0] + bv, acc[i][j][1] + bv);
          u.h2[1] = cvt_pk(acc[i][j][2] + bv, acc[i][j][3] + bv);
          *(f16x4*)(vto + (bh * DK + d) * SEQ + sigma_k(slot0)) = u.h4;
        }
      }
    }
  }
}

// ---------------- out-proj GEMM, DOUBLE-BUFFERED 64x128 tile ---------------------
__global__ __launch_bounds__(256, 2) void k_gemm_out(
    const f16* __restrict__ A, const f16* __restrict__ Bt,
    const float* __restrict__ bias, float* __restrict__ outf, int N, int K)
{
  __shared__ f16 As[2][64][64];    // 16 KB
  __shared__ f16 Bs[2][128][64];   // 32 KB
  const int m0 = blockIdx.y * 64, n0 = blockIdx.x * 128;
  const int t = threadIdx.x;
  const int l = t & 63, w = t >> 6;
  const int lc = l & 15, g = l >> 4;
  const int srow = l >> 3;
  const int ssl  = ((l & 7) ^ srow) * 16;
  const int swz  = (lc & 7) << 4;

  auto stage = [&](int buf, int kt) {
    #pragma unroll
    for (int it = 0; it < 2; ++it) {
      int row = it*32 + w*8 + srow;
      gl_lds16((const char*)(A + (size_t)(m0 + row) * K + kt) + ssl,
               &As[buf][it*32 + w*8][0]);
    }
    #pragma unroll
    for (int it = 0; it < 4; ++it) {
      int row = it*32 + w*8 + srow;
      gl_lds16((const char*)(Bt + (size_t)(n0 + row) * K + kt) + ssl,
               &Bs[buf][it*32 + w*8][0]);
    }
  };

  f32x4 acc[4][2] = {};
  const int NTk = K >> 6;
  stage(0, 0);

  for (int ti = 0; ti < NTk; ++ti) {
    __syncthreads();
    if (ti + 1 < NTk) stage((ti + 1) & 1, (ti + 1) * 64);
    const char* abase = (const char*)&As[ti & 1][0][0];
    const char* bbase = (const char*)&Bs[ti & 1][0][0];
    #pragma unroll
    for (int ks = 0; ks < 64; ks += 32) {
      f16x8 af[4], bf[2];
      #pragma unroll
      for (int i = 0; i < 4; ++i)
        af[i] = *(const f16x8*)(abase + (i*16 + lc)*128 + ((ks*2 + g*16) ^ swz));
      #pragma unroll
      for (int j = 0; j < 2; ++j)
        bf[j] = *(const f16x8*)(bbase + (w*32 + j*16 + lc)*128 + ((ks*2 + g*16) ^ swz));
      #pragma unroll
      for (int i = 0; i < 4; ++i)
        #pragma unroll
        for (int j = 0; j < 2; ++j)
          acc[i][j] = __builtin_amdgcn_mfma_f32_16x16x32_f16(af[i], bf[j], acc[i][j], 0, 0, 0);
    }
  }

  #pragma unroll
  for (int i = 0; i < 4; ++i) {
    #pragma unroll
    for (int j = 0; j < 2; ++j) {
      int col = n0 + w*32 + j*16 + lc;
      float bv = bias[col];
      #pragma unroll
      for (int r = 0; r < 4; ++r) {
        int row = m0 + i*16 + g*4 + r;
        outf[(size_t)row * N + col] = acc[i][j][r] + bv;
      }
    }
  }
}

// ---------------- flash attention v11: compacted keys, 128-key period ------------
// 512 blocks x 256 thr; wave owns 32 q. Period = 2 k-tiles staged per barrier
// (halves barrier/drain count). LDS 64 KB -> still 2 blocks/CU. Guarded sub-tile
// loop never touches rows >= ceil64(cnt).
__global__ __launch_bounds__(256, 2) void k_attn11(
    const f16* __restrict__ Q, const f16* __restrict__ K,
    const f16* __restrict__ Vt, const int* __restrict__ cnt,
    f16* __restrict__ ctx)
{
  __shared__ f16 Kb[2][2][32][128];   // [period-buf][sub-tile][paired-row][256B]
  __shared__ f16 Vb[2][2][32][128];

  const int bid = blockIdx.x;
  const int xcd = bid & 7, slot = bid >> 3;        // slot 0..63
  const int bh = xcd * 4 + (slot >> 4);            // 0..31
  const int qb = slot & 15;
  const int b  = bh >> 4, h = bh & (NHEADS - 1);
  const int t = threadIdx.x, l = t & 63, w = t >> 6;
  const int r31 = l & 31, hi = l >> 5;
  const int Rm = r31 & 15;
  const int q0 = qb * 128 + w * 32;

  const int c = cnt[b];
  const int NTc = (c + 63) >> 6;                   // 64-key tiles
  const int NP  = (NTc + 1) >> 1;                  // 128-key periods

  const f16* Qp = Q + (size_t)bh * SEQ * DK;
  const f16* Kp = K + (size_t)bh * SEQ * DK;
  const f16* Vp = Vt + (size_t)bh * DK * SEQ;

  f16x8 qf[4];
  #pragma unroll
  for (int ds = 0; ds < 4; ++ds)
    qf[ds] = ld_f16x8_g(Qp + (size_t)(q0 + r31) * DK + ds*16 + hi*8);

  f32x16 o[2] = {};
  float mrow = -3e38f;
  float lsum = 0.f;

  auto stage_period = [&](int buf, int pp) {
    #pragma unroll
    for (int j2 = 0; j2 < 2; ++j2) {
      int tile = pp*2 + j2;
      if (tile >= NTc) break;
      int kt = tile * 64;
      #pragma unroll
      for (int cc = 0; cc < 2; ++cc) {
        int Rbase = w*8 + cc*4;
        int R = Rbase + (l >> 4);
        int u = (l & 15) ^ (R & 15);
        int off32 = (u >> 3) * 32;
        int byteoff = (u & 7) * 16;
        gl_lds16((const char*)Kp + (size_t)(kt + off32 + R) * (DK*2) + byteoff,
                 &Kb[buf][j2][Rbase][0]);
        gl_lds16((const char*)Vp + (size_t)(off32 + R) * (SEQ*2) + (size_t)kt*2 + byteoff,
                 &Vb[buf][j2][Rbase][0]);
      }
    }
  };

  stage_period(0, 0);

  for (int pp = 0; pp < NP; ++pp) {
    __syncthreads();                          // period pp's stage complete
    if (pp + 1 < NP) stage_period((pp + 1) & 1, pp + 1);
    const int buf = pp & 1;

    #pragma unroll
    for (int j2 = 0; j2 < 2; ++j2) {
      const int tile = pp*2 + j2;
      if (tile >= NTc) break;
      const int kt = tile * 64;
      const char* kb = (const char*)&Kb[buf][j2][0][0];
      const char* vb = (const char*)&Vb[buf][j2][0][0];

      f32x16 p[2];
      if (kt + 64 <= c) {
        #pragma unroll
        for (int T = 0; T < 2; ++T)
          #pragma unroll
          for (int r = 0; r < 16; ++r) p[T][r] = 0.f;
      } else {
        #pragma unroll
        for (int T = 0; T < 2; ++T)
          #pragma unroll
          for (int r = 0; r < 16; ++r) {
            int k = kt + T*32 + 4*hi + (r & 3) + 8*(r >> 2);
            p[T][r] = (k < c) ? 0.f : MASKVAL;
          }
      }

      __builtin_amdgcn_s_setprio(1);
      #pragma unroll
      for (int T = 0; T < 2; ++T)
        #pragma unroll
        for (int ds = 0; ds < 4; ++ds) {
          int slotc = T*8 + ds*2 + hi;
          f16x8 kf = *(const f16x8*)(kb + r31*256 + ((slotc ^ Rm) << 4));
          p[T] = __builtin_amdgcn_mfma_f32_32x32x16_f16(kf, qf[ds], p[T], 0, 0, 0);
        }
      __builtin_amdgcn_s_setprio(0);

      float mx;
      {
        f32x4 t4;
        #pragma unroll
        for (int r = 0; r < 4; ++r)
          t4[r] = fmaxf(fmaxf(p[0][r], p[0][r+4]), fmaxf(p[0][r+8], p[0][r+12]));
        #pragma unroll
        for (int r = 0; r < 4; ++r)
          t4[r] = fmaxf(t4[r], fmaxf(fmaxf(p[1][r], p[1][r+4]), fmaxf(p[1][r+8], p[1][r+12])));
        mx = fmaxf(fmaxf(t4[0], t4[1]), fmaxf(t4[2], t4[3]));
      }
      mx = fmaxf(mx, __shfl_xor(mx, 32));

      if (!__all(mx <= mrow + 8.f)) {
        float nm = fmaxf(mrow, mx);
        float sc = __builtin_amdgcn_exp2f(mrow - nm);
        mrow = nm;
        lsum *= sc;
        #pragma unroll
        for (int dt = 0; dt < 2; ++dt)
          #pragma unroll
          for (int r = 0; r < 16; ++r) o[dt][r] *= sc;
      }

      f16x2 h2[2][8];
      float s0 = 0.f, s1 = 0.f;
      #pragma unroll
      for (int T = 0; T < 2; ++T)
        #pragma unroll
        for (int rp = 0; rp < 8; ++rp) {
          float e0 = __builtin_amdgcn_exp2f(p[T][2*rp]   - mrow);
          float e1 = __builtin_amdgcn_exp2f(p[T][2*rp+1] - mrow);
          s0 += e0; s1 += e1;
          h2[T][rp] = cvt_pk(e0, e1);
        }
      lsum += s0 + s1;

      __builtin_amdgcn_s_setprio(1);
      #pragma unroll
      for (int T = 0; T < 2; ++T)
        #pragma unroll
        for (int half = 0; half < 2; ++half) {
          union { f16x2 a[4]; f16x8 v8; } pu;
          pu.a[0] = h2[T][half*4+0]; pu.a[1] = h2[T][half*4+1];
          pu.a[2] = h2[T][half*4+2]; pu.a[3] = h2[T][half*4+3];
          int m = T*2 + half;
          #pragma unroll
          for (int dt = 0; dt < 2; ++dt) {
            int slotc = dt*8 + m*2 + hi;
            f16x8 vf = *(const f16x8*)(vb + r31*256 + ((slotc ^ Rm) << 4));
            o[dt] = __builtin_amdgcn_mfma_f32_32x32x16_f16(vf, pu.v8, o[dt], 0, 0, 0);
          }
        }
      __builtin_amdgcn_s_setprio(0);
    }
  }

  lsum += __shfl_xor(lsum, 32);
  float inv = 1.f / lsum;
  f16* cp = ctx + (size_t)(b*SEQ + q0 + r31) * DMODEL + h*DK;
  #pragma unroll
  for (int dt = 0; dt < 2; ++dt)
    #pragma unroll
    for (int rq = 0; rq < 4; ++rq) {
      union { f16x2 h2v[2]; f16x4 h4v; } u;
      u.h2v[0] = cvt_pk(o[dt][4*rq+0]*inv, o[dt][4*rq+1]*inv);
      u.h2v[1] = cvt_pk(o[dt][4*rq+2]*inv, o[dt][4*rq+3]*inv);
      *(f16x4*)(cp + dt*32 + 8*rq + 4*hi) = u.h4v;
    }
}

extern "C" void kernel_launch(void* const* d_in, const int* in_sizes, int n_in,
                              void* d_out, int out_size, void* d_ws, size_t ws_size,
                              hipStream_t stream) {
  const float* x    = (const float*)d_in[0];
  const int*   mask = (const int*)d_in[1];
  const float* Wqkv = (const float*)d_in[2];
  const float* bqkv = (const float*)d_in[3];
  const float* Wout = (const float*)d_in[4];
  const float* bout = (const float*)d_in[5];
  float* out = (float*)d_out;

  const size_t SZ_X    = (size_t)MTOT * DMODEL * 2;
  const size_t SZ_WQKV = (size_t)NQKV * DMODEL * 2;
  const size_t SZ_WOUT = (size_t)DMODEL * DMODEL * 2;
  const size_t SZ_QKV  = (size_t)BATCH * NHEADS * SEQ * DK * 2;
  const size_t SZ_INV  = (size_t)MTOT * 4;    // inv: 4096 ints
  const size_t SZ_CNT  = 256;
  const size_t NEED = SZ_X + SZ_WQKV + SZ_WOUT + 3*SZ_QKV + SZ_X + SZ_INV + SZ_CNT;
  if (ws_size < NEED) return;

  char* p = (char*)d_ws;
  f16* xh    = (f16*)p; p += SZ_X;
  f16* Wqkvt = (f16*)p; p += SZ_WQKV;
  f16* Woutt = (f16*)p; p += SZ_WOUT;
  f16* Qh    = (f16*)p; p += SZ_QKV;
  f16* Kh    = (f16*)p; p += SZ_QKV;
  f16* Vth   = (f16*)p; p += SZ_QKV;
  f16* ctx   = (f16*)p; p += SZ_X;
  int* inv   = (int*)p; p += SZ_INV;
  int* cnt   = (int*)p; p += SZ_CNT;

  k_prep<<<4096 + 3072 + 1024 + BATCH, 256, 0, stream>>>(
      x, xh, Wqkv, Wqkvt, Wout, Woutt, mask, inv, cnt);

  k_gemm_qkv2<<<512 + 1024, 256, 0, stream>>>(
      xh, Wqkvt, bqkv, inv, cnt, Qh, Kh, Vth, DMODEL);

  k_attn11<<<32 * 16, 256, 0, stream>>>(Qh, Kh, Vth, cnt, ctx);

  k_gemm_out<<<dim3(DMODEL/128, MTOT/64), 256, 0, stream>>>(
      ctx, Woutt, bout, out, DMODEL, DMODEL);
}